// Round 2
// baseline (237.664 us; speedup 1.0000x reference)
//
#include <hip/hip_runtime.h>
#include <hip/hip_bf16.h>
#include <math.h>

// COLoRALinear: B=4, S=2048, D_IN=D_OUT=2048, E=8, R=8, SCALING=2.0
#define BATCH 4
#define SEQ   2048
#define DIN   2048
#define DOUT  2048
#define NEXP  8
#define RANK  8
#define MTOT  (BATCH * SEQ)   // 8192
#define KE    64              // expert aug rank (shared LoRA folded into Wb)
#define NKC   8               // split-K chunks in gemm_t

typedef __bf16 bf16x8 __attribute__((ext_vector_type(8)));
typedef __bf16 bf16x4 __attribute__((ext_vector_type(4)));
typedef float  f32x4  __attribute__((ext_vector_type(4)));

#define GLOBAL_AS __attribute__((address_space(1)))
#define LDS_AS    __attribute__((address_space(3)))

// Barrier that is simultaneously a compiler memory fence: nothing can be
// scheduled between the fence and the s_barrier (they are one asm statement).
#define BARRIER() asm volatile("s_barrier" ::: "memory")

// ---------------------------------------------------------------------------
// K1 mega_prep (unchanged, ran fine in round 0): 4736 blocks.
//  [0,512):     gemm_t tiles -> pt partials + plog partial logits + xb bf16
//  [512,4608):  Wb = bf16(W + cw*2*shared_B@shared_A)
//  [4608,4736): caug[o][k] = (1-cw)*2*expert_B[k>>3][o][k&7]
// ---------------------------------------------------------------------------
__global__ __launch_bounds__(256) void mega_prep(
    const float* __restrict__ x, const float* __restrict__ W,
    const float* __restrict__ expert_A, const float* __restrict__ shared_A,
    const float* __restrict__ expert_B, const float* __restrict__ shared_B,
    const float* __restrict__ task_emb, const float* __restrict__ collab,
    __bf16* __restrict__ xb, __bf16* __restrict__ Wb,
    __bf16* __restrict__ caug, __bf16* __restrict__ pt, float* __restrict__ plog)
{
    const int bid = blockIdx.x;
    const int t = threadIdx.x;

    if (bid >= 512) {
        if (bid < 4608) {
            size_t idx = ((size_t)(bid - 512) * 256 + t) * 4;
            int o = (int)(idx >> 11), i = (int)(idx & 2047);
            float cw = 1.0f / (1.0f + expf(-collab[0]));
            float s = cw * 2.0f;
            float4 w = *(const float4*)&W[idx];
            float dx = 0.f, dy = 0.f, dz = 0.f, dw = 0.f;
            #pragma unroll
            for (int r = 0; r < 8; ++r) {
                float bs = shared_B[(size_t)o * RANK + r];
                float4 as = *(const float4*)&shared_A[(size_t)r * DIN + i];
                dx += bs * as.x; dy += bs * as.y; dz += bs * as.z; dw += bs * as.w;
            }
            bf16x4 h = { (__bf16)(w.x + s * dx), (__bf16)(w.y + s * dy),
                         (__bf16)(w.z + s * dz), (__bf16)(w.w + s * dw) };
            *(bf16x4*)&Wb[idx] = h;
        } else {
            int idx = ((bid - 4608) * 256 + t) * 4;   // over 2048*64
            int o = idx >> 6, k = idx & 63;           // k multiple of 4
            float cw = 1.0f / (1.0f + expf(-collab[0]));
            float s = (1.0f - cw) * 2.0f;
            float4 v = *(const float4*)&expert_B[((size_t)(k >> 3) * DOUT + o) * RANK + (k & 7)];
            bf16x4 h = { (__bf16)(s * v.x), (__bf16)(s * v.y),
                         (__bf16)(s * v.z), (__bf16)(s * v.w) };
            *(bf16x4*)&caug[idx] = h;
        }
        return;
    }

    // ---- gemm_t tile ----
    __shared__ __bf16 lsA[128 * 64];
    __shared__ __bf16 lsB[96 * 64];
    __shared__ float lsc[32];
    const int lane = t & 63;
    const int w = t >> 6;                 // wave: rows w*32 .. w*32+31
    const int kc = bid & 7;
    const int m0 = (bid >> 3) * 128;

    f32x4 acc[2][5];
    #pragma unroll
    for (int a = 0; a < 2; ++a)
        #pragma unroll
        for (int c = 0; c < 5; ++c) acc[a][c] = (f32x4){0.f, 0.f, 0.f, 0.f};

    for (int it = 0; it < 4; ++it) {
        int k0 = kc * 256 + it * 64;
        // A staging: x fp32 -> bf16 -> swizzled LDS + xb global store
        #pragma unroll
        for (int q = 0; q < 4; ++q) {
            int row = q * 32 + (t >> 3), sl = t & 7, seg = sl ^ (row & 7);
            const float* gp = x + (size_t)(m0 + row) * DIN + k0 + seg * 8;
            float4 v0 = *(const float4*)gp;
            float4 v1 = *(const float4*)(gp + 4);
            bf16x8 h = { (__bf16)v0.x, (__bf16)v0.y, (__bf16)v0.z, (__bf16)v0.w,
                         (__bf16)v1.x, (__bf16)v1.y, (__bf16)v1.z, (__bf16)v1.w };
            *(bf16x8*)&lsA[row * 64 + sl * 8] = h;
            *(bf16x8*)&xb[(size_t)(m0 + row) * DIN + k0 + seg * 8] = h;
        }
        // B staging: rows 0-63 expert_A, 64-71 task_emb, >=72 zero
        #pragma unroll
        for (int q = 0; q < 3; ++q) {
            int c = q * 256 + t;
            int row = c >> 3, sl = c & 7, seg = sl ^ (row & 7);
            bf16x8 h = { (__bf16)0.f, (__bf16)0.f, (__bf16)0.f, (__bf16)0.f,
                         (__bf16)0.f, (__bf16)0.f, (__bf16)0.f, (__bf16)0.f };
            if (row < 64) {
                const float* gp = expert_A + (size_t)row * DIN + k0 + seg * 8;
                float4 v0 = *(const float4*)gp, v1 = *(const float4*)(gp + 4);
                h = bf16x8{ (__bf16)v0.x, (__bf16)v0.y, (__bf16)v0.z, (__bf16)v0.w,
                            (__bf16)v1.x, (__bf16)v1.y, (__bf16)v1.z, (__bf16)v1.w };
            } else if (row < 72) {
                const float* gp = task_emb + (size_t)(row - 64) * DIN + k0 + seg * 8;
                float4 v0 = *(const float4*)gp, v1 = *(const float4*)(gp + 4);
                h = bf16x8{ (__bf16)v0.x, (__bf16)v0.y, (__bf16)v0.z, (__bf16)v0.w,
                            (__bf16)v1.x, (__bf16)v1.y, (__bf16)v1.z, (__bf16)v1.w };
            }
            *(bf16x8*)&lsB[row * 64 + sl * 8] = h;
        }
        __syncthreads();
        #pragma unroll
        for (int kk = 0; kk < 2; ++kk) {
            bf16x8 af[2], bfr[5];
            #pragma unroll
            for (int tm = 0; tm < 2; ++tm) {
                int r = w * 32 + tm * 16 + (lane & 15);
                int slot = (kk * 4 + (lane >> 4)) ^ (r & 7);
                af[tm] = *(const bf16x8*)&lsA[r * 64 + slot * 8];
            }
            #pragma unroll
            for (int tn = 0; tn < 5; ++tn) {
                int r = tn * 16 + (lane & 15);
                int slot = (kk * 4 + (lane >> 4)) ^ (r & 7);
                bfr[tn] = *(const bf16x8*)&lsB[r * 64 + slot * 8];
            }
            #pragma unroll
            for (int tm = 0; tm < 2; ++tm)
                #pragma unroll
                for (int tn = 0; tn < 5; ++tn)
                    acc[tm][tn] = __builtin_amdgcn_mfma_f32_16x16x32_bf16(
                        af[tm], bfr[tn], acc[tm][tn], 0, 0, 0);
        }
        __syncthreads();
    }

    // pt stores (cols 0-63)
    #pragma unroll
    for (int tm = 0; tm < 2; ++tm)
        #pragma unroll
        for (int tn = 0; tn < 4; ++tn) {
            int col = tn * 16 + (lane & 15);
            #pragma unroll
            for (int v = 0; v < 4; ++v) {
                int row = m0 + w * 32 + tm * 16 + (lane >> 4) * 4 + v;
                pt[((size_t)kc * MTOT + row) * KE + col] = (__bf16)acc[tm][tn][v];
            }
        }

    // partial logits (cols 64-71 live in frag tn=4, lanes with (lane&15)<8)
    float s = 0.f;
    #pragma unroll
    for (int tm = 0; tm < 2; ++tm)
        #pragma unroll
        for (int v = 0; v < 4; ++v) s += acc[tm][4][v];
    s += __shfl_down(s, 32);
    s += __shfl_down(s, 16);
    if (lane < 8) lsc[w * 8 + lane] = s;
    __syncthreads();
    if (t < 8)
        plog[bid * 8 + t] = lsc[t] + lsc[8 + t] + lsc[16 + t] + lsc[24 + t];
}

// ---------------------------------------------------------------------------
// K2 gemm_main: 256x256 tile, 8 waves (512 thr), phase-locked pipeline.
//   out = xb @ Wb^T + (softmax-scaled t) @ caug^T + bias
// Ring-2 LDS K-tile buffers (128 KiB), BK=64. Per K-tile: issue ALL 8
// global_load_lds for the NEXT tile at phase 0 (issue-to-drain = 4 compute
// phases), then 4 phases {ds_read A-frags -> BARRIER -> setprio(1) 16 MFMA
// setprio(0) -> BARRIER}; single vmcnt(0) right before the tile's last
// barrier (the DMA was issued a full tile earlier, so the wait is ~free).
// All barriers are asm("s_barrier":::"memory") — fence+barrier fused, so the
// scheduler can never hoist a ds_read past the drain (m152 race class).
// XOR-swizzled LDS via pre-swizzled global source (0-conflict scheme).
// Grid 256 blocks 1-D: n-tile = bid&7 pins one Wb panel per XCD L2.
// ---------------------------------------------------------------------------
__global__ __launch_bounds__(512, 2) void gemm_main(
    const __bf16* __restrict__ xb, const __bf16* __restrict__ Wb,
    const __bf16* __restrict__ pt, const __bf16* __restrict__ caug,
    const float* __restrict__ plog, const float* __restrict__ bias,
    float* __restrict__ out)
{
    __shared__ __bf16 lds[65536];   // 128 KiB: elements [A0|A1|B0|B1] 16K each
    const int t = threadIdx.x;
    const int lane = t & 63;
    const int wid = t >> 6;
    const int wm = wid >> 2, wn = wid & 3;      // 2x4 wave grid, 128x64 per wave
    const int bid = blockIdx.x;
    const int n0 = (bid & 7) * 256;             // XCD-pinned Wb panel
    const int m0 = (bid >> 3) * 256;
    const int b  = m0 >> 11;

    // staging addressing (pre-swizzled source -> linear LDS fill)
    const int srow = t >> 3;                    // 0..63
    const int sseg = (t & 7) ^ (srow & 7);
    const __bf16* gA = xb + (size_t)(m0 + srow) * DIN + sseg * 8;
    const __bf16* gB = Wb + (size_t)(n0 + srow) * DIN + sseg * 8;
    const int lbase = (t & ~63) * 8;            // wave-uniform LDS element base

    // fragment ds_read offsets (^32 flips slot bit2: other K-half)
    int aoff[8], boff[4];
    #pragma unroll
    for (int fm = 0; fm < 8; ++fm) {
        int r = wm * 128 + fm * 16 + (lane & 15);
        aoff[fm] = r * 64 + (((lane >> 4) ^ (r & 7)) * 8);
    }
    #pragma unroll
    for (int fn = 0; fn < 4; ++fn) {
        int r = wn * 64 + fn * 16 + (lane & 15);
        boff[fn] = r * 64 + (((lane >> 4) ^ (r & 7)) * 8);
    }

    f32x4 acc[8][4];
    #pragma unroll
    for (int i = 0; i < 8; ++i)
        #pragma unroll
        for (int j = 0; j < 4; ++j) acc[i][j] = (f32x4){0.f, 0.f, 0.f, 0.f};

    // prologue: stage K-tile 0 into buffer 0
    #pragma unroll
    for (int q = 0; q < 4; ++q) {
        __builtin_amdgcn_global_load_lds((GLOBAL_AS void*)(gA + q * 64 * DIN),
            (LDS_AS void*)&lds[q * 4096 + lbase], 16, 0, 0);
        __builtin_amdgcn_global_load_lds((GLOBAL_AS void*)(gB + q * 64 * DIN),
            (LDS_AS void*)&lds[32768 + q * 4096 + lbase], 16, 0, 0);
    }
    asm volatile("s_waitcnt vmcnt(0)" ::: "memory");
    BARRIER();

    // ---- main loop: K = 2048, 32 K-tiles of BK=64 ----
    for (int kt = 0; kt < 32; ++kt) {
        const int abase = (kt & 1) * 16384;
        const int bbase = 32768 + (kt & 1) * 16384;
        // prefetch next K-tile into the other buffer (issued a full tile early)
        if (kt < 31) {
            const int nb = ((kt & 1) ^ 1) * 16384;
            const __bf16* a2 = gA + (kt + 1) * 64;
            const __bf16* b2 = gB + (kt + 1) * 64;
            #pragma unroll
            for (int q = 0; q < 4; ++q) {
                __builtin_amdgcn_global_load_lds((GLOBAL_AS void*)(a2 + q * 64 * DIN),
                    (LDS_AS void*)&lds[nb + q * 4096 + lbase], 16, 0, 0);
                __builtin_amdgcn_global_load_lds((GLOBAL_AS void*)(b2 + q * 64 * DIN),
                    (LDS_AS void*)&lds[32768 + nb + q * 4096 + lbase], 16, 0, 0);
            }
        }
        // phase 0 extra: the wave's full B slice for this K-tile (8 reads, regs)
        bf16x8 bfrag[4][2];
        #pragma unroll
        for (int fn = 0; fn < 4; ++fn) {
            bfrag[fn][0] = *(const bf16x8*)&lds[bbase + boff[fn]];
            bfrag[fn][1] = *(const bf16x8*)&lds[bbase + (boff[fn] ^ 32)];
        }
        #pragma unroll
        for (int p = 0; p < 4; ++p) {
            bf16x8 afr[2][2];
            #pragma unroll
            for (int i = 0; i < 2; ++i) {
                int fm = p * 2 + i;
                afr[i][0] = *(const bf16x8*)&lds[abase + aoff[fm]];
                afr[i][1] = *(const bf16x8*)&lds[abase + (aoff[fm] ^ 32)];
            }
            BARRIER();
            __builtin_amdgcn_s_setprio(1);
            #pragma unroll
            for (int kk = 0; kk < 2; ++kk)
                #pragma unroll
                for (int i = 0; i < 2; ++i)
                    #pragma unroll
                    for (int fn = 0; fn < 4; ++fn)
                        acc[p * 2 + i][fn] = __builtin_amdgcn_mfma_f32_16x16x32_bf16(
                            afr[i][kk], bfrag[fn][kk], acc[p * 2 + i][fn], 0, 0, 0);
            __builtin_amdgcn_s_setprio(0);
            if (p == 3 && kt < 31)
                asm volatile("s_waitcnt vmcnt(0)" ::: "memory");
            BARRIER();
        }
    }

    // ---- correction phase (LDS buffers now free) ----
    // (a) caug -> B0 region (DMA, drained before (d))
    {
        const __bf16* gC = caug + (size_t)(n0 + srow) * KE + sseg * 8;
        #pragma unroll
        for (int q = 0; q < 4; ++q)
            __builtin_amdgcn_global_load_lds((GLOBAL_AS void*)(gC + q * 64 * KE),
                (LDS_AS void*)&lds[32768 + q * 4096 + lbase], 16, 0, 0);
    }
    // (b) logits: sum plog[b*128 .. +128][8] -> softmax factors f[8]
    float* scr = (float*)&lds[16384];           // overlay on A1 (512 + 8 f32)
    float* lgs = scr + 512;
    {
        const float* pb = plog + (size_t)b * 128 * 8;
        int e = t & 7, rr = t >> 3;             // rr 0..63
        scr[rr * 8 + e] = pb[rr * 8 + e] + pb[(rr + 64) * 8 + e];
    }
    asm volatile("s_waitcnt lgkmcnt(0)" ::: "memory");
    BARRIER();
    if (t < 8) {
        float s = 0.f;
        #pragma unroll
        for (int i = 0; i < 64; ++i) s += scr[i * 8 + t];
        lgs[t] = s;
    }
    asm volatile("s_waitcnt lgkmcnt(0)" ::: "memory");
    BARRIER();
    float f[NEXP];
    {
        float li[NEXP];
        #pragma unroll
        for (int e = 0; e < NEXP; ++e) li[e] = lgs[e] * (1.0f / (float)SEQ);
        float mx = li[0];
        #pragma unroll
        for (int e = 1; e < NEXP; ++e) mx = fmaxf(mx, li[e]);
        float den = 0.f;
        #pragma unroll
        for (int e = 0; e < NEXP; ++e) { f[e] = expf(li[e] - mx); den += f[e]; }
        float rden = 1.0f / den;
        #pragma unroll
        for (int e = 0; e < NEXP; ++e) f[e] *= rden;
    }
    // (c) build scaled tb tile into A0 (swizzled layout the readers expect)
    #pragma unroll
    for (int q = 0; q < 4; ++q) {
        int row = q * 64 + srow;
        const __bf16* p0 = pt + (size_t)(m0 + row) * KE + sseg * 8;
        float sum[8] = {0.f, 0.f, 0.f, 0.f, 0.f, 0.f, 0.f, 0.f};
        #pragma unroll
        for (int kc = 0; kc < NKC; ++kc) {
            bf16x8 v = *(const bf16x8*)(p0 + (size_t)kc * MTOT * KE);
            #pragma unroll
            for (int j = 0; j < 8; ++j) sum[j] += (float)v[j];
        }
        float fe = f[sseg];                     // chunk spans exactly one expert
        bf16x8 h;
        #pragma unroll
        for (int j = 0; j < 8; ++j) h[j] = (__bf16)(sum[j] * fe);
        *(bf16x8*)&lds[row * 64 + (t & 7) * 8] = h;
    }
    asm volatile("s_waitcnt vmcnt(0) lgkmcnt(0)" ::: "memory");
    BARRIER();
    // (d) correction MFMAs (K=64)
    {
        bf16x8 bfrag[4][2];
        #pragma unroll
        for (int fn = 0; fn < 4; ++fn) {
            bfrag[fn][0] = *(const bf16x8*)&lds[32768 + boff[fn]];
            bfrag[fn][1] = *(const bf16x8*)&lds[32768 + (boff[fn] ^ 32)];
        }
        #pragma unroll
        for (int fm = 0; fm < 8; ++fm) {
            bf16x8 a0 = *(const bf16x8*)&lds[aoff[fm]];
            bf16x8 a1 = *(const bf16x8*)&lds[aoff[fm] ^ 32];
            #pragma unroll
            for (int fn = 0; fn < 4; ++fn) {
                acc[fm][fn] = __builtin_amdgcn_mfma_f32_16x16x32_bf16(
                    a0, bfrag[fn][0], acc[fm][fn], 0, 0, 0);
                acc[fm][fn] = __builtin_amdgcn_mfma_f32_16x16x32_bf16(
                    a1, bfrag[fn][1], acc[fm][fn], 0, 0, 0);
            }
        }
    }

    // ---- epilogue: bias + fp32 store ----
    #pragma unroll
    for (int fn = 0; fn < 4; ++fn) {
        int col = n0 + wn * 64 + fn * 16 + (lane & 15);
        float bv = bias[col];
        #pragma unroll
        for (int fm = 0; fm < 8; ++fm) {
            int row = m0 + wm * 128 + fm * 16 + (lane >> 4) * 4;
            #pragma unroll
            for (int v = 0; v < 4; ++v)
                out[(size_t)(row + v) * DOUT + col] = acc[fm][fn][v] + bv;
        }
    }
}

// ---------------------------------------------------------------------------
// Workspace (bytes):
//   xb   @ 0         : 33,554,432   (8192x2048 bf16)
//   Wb   @ 33554432  :  8,388,608   (2048x2048 bf16, shared LoRA folded)
//   pt   @ 41943040  :  8,388,608   (8x8192x64 bf16)
//   caug @ 50331648  :    262,144   (2048x64 bf16)
//   plog @ 50593792  :     16,384   (512x8 f32, fully overwritten)
// ---------------------------------------------------------------------------
extern "C" void kernel_launch(void* const* d_in, const int* in_sizes, int n_in,
                              void* d_out, int out_size, void* d_ws, size_t ws_size,
                              hipStream_t stream)
{
    const float* x        = (const float*)d_in[0];
    const float* base_W   = (const float*)d_in[1];
    const float* base_b   = (const float*)d_in[2];
    const float* shared_A = (const float*)d_in[3];
    const float* shared_B = (const float*)d_in[4];
    const float* expert_A = (const float*)d_in[5];
    const float* expert_B = (const float*)d_in[6];
    const float* task_emb = (const float*)d_in[7];
    const float* collab_w = (const float*)d_in[8];
    float* out = (float*)d_out;

    char* ws = (char*)d_ws;
    __bf16* xb   = (__bf16*)(ws + 0);
    __bf16* Wb   = (__bf16*)(ws + 33554432);
    __bf16* pt   = (__bf16*)(ws + 41943040);
    __bf16* caug = (__bf16*)(ws + 50331648);
    float*  plog = (float*) (ws + 50593792);

    mega_prep<<<dim3(4736), 256, 0, stream>>>(x, base_W, expert_A, shared_A,
                                              expert_B, shared_B, task_emb, collab_w,
                                              xb, Wb, caug, pt, plog);
    gemm_main<<<dim3(256), 512, 0, stream>>>(xb, Wb, pt, caug, plog, base_b, out);
}

// Round 5
// 234.029 us; speedup vs baseline: 1.0155x; 1.0155x over previous
//
#include <hip/hip_runtime.h>
#include <hip/hip_bf16.h>
#include <math.h>

// COLoRALinear: B=4, S=2048, D_IN=D_OUT=2048, E=8, R=8, SCALING=2.0
#define BATCH 4
#define SEQ   2048
#define DIN   2048
#define DOUT  2048
#define NEXP  8
#define RANK  8
#define MTOT  (BATCH * SEQ)   // 8192
#define KE    64              // expert aug rank (shared LoRA folded into Wb)
#define NKC   8               // split-K chunks in gemm_t

typedef __bf16 bf16x8 __attribute__((ext_vector_type(8)));
typedef __bf16 bf16x4 __attribute__((ext_vector_type(4)));
typedef float  f32x4  __attribute__((ext_vector_type(4)));

#define GLOBAL_AS __attribute__((address_space(1)))
#define LDS_AS    __attribute__((address_space(3)))

// Barrier fused with a compiler memory fence (no op can slip between them).
#define BARRIER() asm volatile("s_barrier" ::: "memory")

// ---------------------------------------------------------------------------
// K1 mega_prep (unchanged, passed rounds 0 and 2): 4736 blocks.
// ---------------------------------------------------------------------------
__global__ __launch_bounds__(256) void mega_prep(
    const float* __restrict__ x, const float* __restrict__ W,
    const float* __restrict__ expert_A, const float* __restrict__ shared_A,
    const float* __restrict__ expert_B, const float* __restrict__ shared_B,
    const float* __restrict__ task_emb, const float* __restrict__ collab,
    __bf16* __restrict__ xb, __bf16* __restrict__ Wb,
    __bf16* __restrict__ caug, __bf16* __restrict__ pt, float* __restrict__ plog)
{
    const int bid = blockIdx.x;
    const int t = threadIdx.x;

    if (bid >= 512) {
        if (bid < 4608) {
            size_t idx = ((size_t)(bid - 512) * 256 + t) * 4;
            int o = (int)(idx >> 11), i = (int)(idx & 2047);
            float cw = 1.0f / (1.0f + expf(-collab[0]));
            float s = cw * 2.0f;
            float4 w = *(const float4*)&W[idx];
            float dx = 0.f, dy = 0.f, dz = 0.f, dw = 0.f;
            #pragma unroll
            for (int r = 0; r < 8; ++r) {
                float bs = shared_B[(size_t)o * RANK + r];
                float4 as = *(const float4*)&shared_A[(size_t)r * DIN + i];
                dx += bs * as.x; dy += bs * as.y; dz += bs * as.z; dw += bs * as.w;
            }
            bf16x4 h = { (__bf16)(w.x + s * dx), (__bf16)(w.y + s * dy),
                         (__bf16)(w.z + s * dz), (__bf16)(w.w + s * dw) };
            *(bf16x4*)&Wb[idx] = h;
        } else {
            int idx = ((bid - 4608) * 256 + t) * 4;   // over 2048*64
            int o = idx >> 6, k = idx & 63;           // k multiple of 4
            float cw = 1.0f / (1.0f + expf(-collab[0]));
            float s = (1.0f - cw) * 2.0f;
            float4 v = *(const float4*)&expert_B[((size_t)(k >> 3) * DOUT + o) * RANK + (k & 7)];
            bf16x4 h = { (__bf16)(s * v.x), (__bf16)(s * v.y),
                         (__bf16)(s * v.z), (__bf16)(s * v.w) };
            *(bf16x4*)&caug[idx] = h;
        }
        return;
    }

    // ---- gemm_t tile ----
    __shared__ __bf16 lsA[128 * 64];
    __shared__ __bf16 lsB[96 * 64];
    __shared__ float lsc[32];
    const int lane = t & 63;
    const int w = t >> 6;
    const int kc = bid & 7;
    const int m0 = (bid >> 3) * 128;

    f32x4 acc[2][5];
    #pragma unroll
    for (int a = 0; a < 2; ++a)
        #pragma unroll
        for (int c = 0; c < 5; ++c) acc[a][c] = (f32x4){0.f, 0.f, 0.f, 0.f};

    for (int it = 0; it < 4; ++it) {
        int k0 = kc * 256 + it * 64;
        #pragma unroll
        for (int q = 0; q < 4; ++q) {
            int row = q * 32 + (t >> 3), sl = t & 7, seg = sl ^ (row & 7);
            const float* gp = x + (size_t)(m0 + row) * DIN + k0 + seg * 8;
            float4 v0 = *(const float4*)gp;
            float4 v1 = *(const float4*)(gp + 4);
            bf16x8 h = { (__bf16)v0.x, (__bf16)v0.y, (__bf16)v0.z, (__bf16)v0.w,
                         (__bf16)v1.x, (__bf16)v1.y, (__bf16)v1.z, (__bf16)v1.w };
            *(bf16x8*)&lsA[row * 64 + sl * 8] = h;
            *(bf16x8*)&xb[(size_t)(m0 + row) * DIN + k0 + seg * 8] = h;
        }
        #pragma unroll
        for (int q = 0; q < 3; ++q) {
            int c = q * 256 + t;
            int row = c >> 3, sl = c & 7, seg = sl ^ (row & 7);
            bf16x8 h = { (__bf16)0.f, (__bf16)0.f, (__bf16)0.f, (__bf16)0.f,
                         (__bf16)0.f, (__bf16)0.f, (__bf16)0.f, (__bf16)0.f };
            if (row < 64) {
                const float* gp = expert_A + (size_t)row * DIN + k0 + seg * 8;
                float4 v0 = *(const float4*)gp, v1 = *(const float4*)(gp + 4);
                h = bf16x8{ (__bf16)v0.x, (__bf16)v0.y, (__bf16)v0.z, (__bf16)v0.w,
                            (__bf16)v1.x, (__bf16)v1.y, (__bf16)v1.z, (__bf16)v1.w };
            } else if (row < 72) {
                const float* gp = task_emb + (size_t)(row - 64) * DIN + k0 + seg * 8;
                float4 v0 = *(const float4*)gp, v1 = *(const float4*)(gp + 4);
                h = bf16x8{ (__bf16)v0.x, (__bf16)v0.y, (__bf16)v0.z, (__bf16)v0.w,
                            (__bf16)v1.x, (__bf16)v1.y, (__bf16)v1.z, (__bf16)v1.w };
            }
            *(bf16x8*)&lsB[row * 64 + sl * 8] = h;
        }
        __syncthreads();
        #pragma unroll
        for (int kk = 0; kk < 2; ++kk) {
            bf16x8 af[2], bfr[5];
            #pragma unroll
            for (int tm = 0; tm < 2; ++tm) {
                int r = w * 32 + tm * 16 + (lane & 15);
                int slot = (kk * 4 + (lane >> 4)) ^ (r & 7);
                af[tm] = *(const bf16x8*)&lsA[r * 64 + slot * 8];
            }
            #pragma unroll
            for (int tn = 0; tn < 5; ++tn) {
                int r = tn * 16 + (lane & 15);
                int slot = (kk * 4 + (lane >> 4)) ^ (r & 7);
                bfr[tn] = *(const bf16x8*)&lsB[r * 64 + slot * 8];
            }
            #pragma unroll
            for (int tm = 0; tm < 2; ++tm)
                #pragma unroll
                for (int tn = 0; tn < 5; ++tn)
                    acc[tm][tn] = __builtin_amdgcn_mfma_f32_16x16x32_bf16(
                        af[tm], bfr[tn], acc[tm][tn], 0, 0, 0);
        }
        __syncthreads();
    }

    #pragma unroll
    for (int tm = 0; tm < 2; ++tm)
        #pragma unroll
        for (int tn = 0; tn < 4; ++tn) {
            int col = tn * 16 + (lane & 15);
            #pragma unroll
            for (int v = 0; v < 4; ++v) {
                int row = m0 + w * 32 + tm * 16 + (lane >> 4) * 4 + v;
                pt[((size_t)kc * MTOT + row) * KE + col] = (__bf16)acc[tm][tn][v];
            }
        }

    float s = 0.f;
    #pragma unroll
    for (int tm = 0; tm < 2; ++tm)
        #pragma unroll
        for (int v = 0; v < 4; ++v) s += acc[tm][4][v];
    s += __shfl_down(s, 32);
    s += __shfl_down(s, 16);
    if (lane < 8) lsc[w * 8 + lane] = s;
    __syncthreads();
    if (t < 8)
        plog[bid * 8 + t] = lsc[t] + lsc[8 + t] + lsc[16 + t] + lsc[24 + t];
}

// ---------------------------------------------------------------------------
// K2 gemm_main: ROUND-2 PASSING SKELETON (256x256 tile, 8 waves, ring-2 LDS,
// 4 phases/K-tile, fused asm barriers, vmcnt(0) drain once per K-tile),
// with ONLY the grid map changed:
//   OLD: n0=(bid&7)*256 -> every XCD re-read ALL of xb (FETCH 168MB, the
//        per-K-tile memory supply 16MB/2.6us == measured wall time).
//   NEW: XCD x owns a 4m x 8n rectangle: m0=(x*4 + (j>>3))*256, n0=(j&7)*256.
//        Per-XCD unique slice/K-tile = 384KB (fits L2); A-rows shared by 8
//        blocks, B-cols by 4 blocks within one L2.
// Everything else byte-identical to the harness-verified round-2 version.
// ---------------------------------------------------------------------------
__global__ __launch_bounds__(512, 2) void gemm_main(
    const __bf16* __restrict__ xb, const __bf16* __restrict__ Wb,
    const __bf16* __restrict__ pt, const __bf16* __restrict__ caug,
    const float* __restrict__ plog, const float* __restrict__ bias,
    float* __restrict__ out)
{
    __shared__ __bf16 lds[65536];   // 128 KiB: elements [A0|A1|B0|B1] 16K each
    const int t = threadIdx.x;
    const int lane = t & 63;
    const int wid = t >> 6;
    const int wm = wid >> 2, wn = wid & 3;      // 2x4 wave grid, 128x64 per wave
    const int bid = blockIdx.x;
    const int xcd = bid & 7, j = bid >> 3;
    const int m0 = (xcd * 4 + (j >> 3)) * 256;  // 4 m-tiles per XCD
    const int n0 = (j & 7) * 256;               // all 8 n-tiles per XCD
    const int b  = m0 >> 11;

    // staging addressing (pre-swizzled source -> linear LDS fill)
    const int srow = t >> 3;                    // 0..63
    const int sseg = (t & 7) ^ (srow & 7);
    const __bf16* gA = xb + (size_t)(m0 + srow) * DIN + sseg * 8;
    const __bf16* gB = Wb + (size_t)(n0 + srow) * DIN + sseg * 8;
    const int lbase = (t & ~63) * 8;            // wave-uniform LDS element base

    // fragment ds_read offsets (^32 flips slot bit2: other K-half)
    int aoff[8], boff[4];
    #pragma unroll
    for (int fm = 0; fm < 8; ++fm) {
        int r = wm * 128 + fm * 16 + (lane & 15);
        aoff[fm] = r * 64 + (((lane >> 4) ^ (r & 7)) * 8);
    }
    #pragma unroll
    for (int fn = 0; fn < 4; ++fn) {
        int r = wn * 64 + fn * 16 + (lane & 15);
        boff[fn] = r * 64 + (((lane >> 4) ^ (r & 7)) * 8);
    }

    f32x4 acc[8][4];
    #pragma unroll
    for (int i = 0; i < 8; ++i)
        #pragma unroll
        for (int jj = 0; jj < 4; ++jj) acc[i][jj] = (f32x4){0.f, 0.f, 0.f, 0.f};

    // prologue: stage K-tile 0 into buffer 0
    #pragma unroll
    for (int q = 0; q < 4; ++q) {
        __builtin_amdgcn_global_load_lds((GLOBAL_AS void*)(gA + q * 64 * DIN),
            (LDS_AS void*)&lds[q * 4096 + lbase], 16, 0, 0);
        __builtin_amdgcn_global_load_lds((GLOBAL_AS void*)(gB + q * 64 * DIN),
            (LDS_AS void*)&lds[32768 + q * 4096 + lbase], 16, 0, 0);
    }
    asm volatile("s_waitcnt vmcnt(0)" ::: "memory");
    BARRIER();

    // ---- main loop: K = 2048, 32 K-tiles of BK=64 ----
    for (int kt = 0; kt < 32; ++kt) {
        const int abase = (kt & 1) * 16384;
        const int bbase = 32768 + (kt & 1) * 16384;
        // prefetch next K-tile into the other buffer (issued a full tile early)
        if (kt < 31) {
            const int nb = ((kt & 1) ^ 1) * 16384;
            const __bf16* a2 = gA + (kt + 1) * 64;
            const __bf16* b2 = gB + (kt + 1) * 64;
            #pragma unroll
            for (int q = 0; q < 4; ++q) {
                __builtin_amdgcn_global_load_lds((GLOBAL_AS void*)(a2 + q * 64 * DIN),
                    (LDS_AS void*)&lds[nb + q * 4096 + lbase], 16, 0, 0);
                __builtin_amdgcn_global_load_lds((GLOBAL_AS void*)(b2 + q * 64 * DIN),
                    (LDS_AS void*)&lds[32768 + nb + q * 4096 + lbase], 16, 0, 0);
            }
        }
        // phase 0 extra: the wave's full B slice for this K-tile (8 reads, regs)
        bf16x8 bfrag[4][2];
        #pragma unroll
        for (int fn = 0; fn < 4; ++fn) {
            bfrag[fn][0] = *(const bf16x8*)&lds[bbase + boff[fn]];
            bfrag[fn][1] = *(const bf16x8*)&lds[bbase + (boff[fn] ^ 32)];
        }
        #pragma unroll
        for (int p = 0; p < 4; ++p) {
            bf16x8 afr[2][2];
            #pragma unroll
            for (int i = 0; i < 2; ++i) {
                int fm = p * 2 + i;
                afr[i][0] = *(const bf16x8*)&lds[abase + aoff[fm]];
                afr[i][1] = *(const bf16x8*)&lds[abase + (aoff[fm] ^ 32)];
            }
            BARRIER();
            __builtin_amdgcn_s_setprio(1);
            #pragma unroll
            for (int kk = 0; kk < 2; ++kk)
                #pragma unroll
                for (int i = 0; i < 2; ++i)
                    #pragma unroll
                    for (int fn = 0; fn < 4; ++fn)
                        acc[p * 2 + i][fn] = __builtin_amdgcn_mfma_f32_16x16x32_bf16(
                            afr[i][kk], bfrag[fn][kk], acc[p * 2 + i][fn], 0, 0, 0);
            __builtin_amdgcn_s_setprio(0);
            if (p == 3 && kt < 31)
                asm volatile("s_waitcnt vmcnt(0)" ::: "memory");
            BARRIER();
        }
    }

    // ---- correction phase (LDS buffers now free) ----
    // (a) caug -> B0 region (DMA, drained before (d))
    {
        const __bf16* gC = caug + (size_t)(n0 + srow) * KE + sseg * 8;
        #pragma unroll
        for (int q = 0; q < 4; ++q)
            __builtin_amdgcn_global_load_lds((GLOBAL_AS void*)(gC + q * 64 * KE),
                (LDS_AS void*)&lds[32768 + q * 4096 + lbase], 16, 0, 0);
    }
    // (b) logits: sum plog[b*128 .. +128][8] -> softmax factors f[8]
    float* scr = (float*)&lds[16384];           // overlay on A1 (512 + 8 f32)
    float* lgs = scr + 512;
    {
        const float* pb = plog + (size_t)b * 128 * 8;
        int e = t & 7, rr = t >> 3;             // rr 0..63
        scr[rr * 8 + e] = pb[rr * 8 + e] + pb[(rr + 64) * 8 + e];
    }
    asm volatile("s_waitcnt lgkmcnt(0)" ::: "memory");
    BARRIER();
    if (t < 8) {
        float s = 0.f;
        #pragma unroll
        for (int i = 0; i < 64; ++i) s += scr[i * 8 + t];
        lgs[t] = s;
    }
    asm volatile("s_waitcnt lgkmcnt(0)" ::: "memory");
    BARRIER();
    float f[NEXP];
    {
        float li[NEXP];
        #pragma unroll
        for (int e = 0; e < NEXP; ++e) li[e] = lgs[e] * (1.0f / (float)SEQ);
        float mx = li[0];
        #pragma unroll
        for (int e = 1; e < NEXP; ++e) mx = fmaxf(mx, li[e]);
        float den = 0.f;
        #pragma unroll
        for (int e = 0; e < NEXP; ++e) { f[e] = expf(li[e] - mx); den += f[e]; }
        float rden = 1.0f / den;
        #pragma unroll
        for (int e = 0; e < NEXP; ++e) f[e] *= rden;
    }
    // (c) build scaled tb tile into A0 (swizzled layout the readers expect)
    #pragma unroll
    for (int q = 0; q < 4; ++q) {
        int row = q * 64 + srow;
        const __bf16* p0 = pt + (size_t)(m0 + row) * KE + sseg * 8;
        float sum[8] = {0.f, 0.f, 0.f, 0.f, 0.f, 0.f, 0.f, 0.f};
        #pragma unroll
        for (int kc = 0; kc < NKC; ++kc) {
            bf16x8 v = *(const bf16x8*)(p0 + (size_t)kc * MTOT * KE);
            #pragma unroll
            for (int jj = 0; jj < 8; ++jj) sum[jj] += (float)v[jj];
        }
        float fe = f[sseg];                     // chunk spans exactly one expert
        bf16x8 h;
        #pragma unroll
        for (int jj = 0; jj < 8; ++jj) h[jj] = (__bf16)(sum[jj] * fe);
        *(bf16x8*)&lds[row * 64 + (t & 7) * 8] = h;
    }
    asm volatile("s_waitcnt vmcnt(0) lgkmcnt(0)" ::: "memory");
    BARRIER();
    // (d) correction MFMAs (K=64)
    {
        bf16x8 bfrag[4][2];
        #pragma unroll
        for (int fn = 0; fn < 4; ++fn) {
            bfrag[fn][0] = *(const bf16x8*)&lds[32768 + boff[fn]];
            bfrag[fn][1] = *(const bf16x8*)&lds[32768 + (boff[fn] ^ 32)];
        }
        #pragma unroll
        for (int fm = 0; fm < 8; ++fm) {
            bf16x8 a0 = *(const bf16x8*)&lds[aoff[fm]];
            bf16x8 a1 = *(const bf16x8*)&lds[aoff[fm] ^ 32];
            #pragma unroll
            for (int fn = 0; fn < 4; ++fn) {
                acc[fm][fn] = __builtin_amdgcn_mfma_f32_16x16x32_bf16(
                    a0, bfrag[fn][0], acc[fm][fn], 0, 0, 0);
                acc[fm][fn] = __builtin_amdgcn_mfma_f32_16x16x32_bf16(
                    a1, bfrag[fn][1], acc[fm][fn], 0, 0, 0);
            }
        }
    }

    // ---- epilogue: bias + fp32 store ----
    #pragma unroll
    for (int fn = 0; fn < 4; ++fn) {
        int col = n0 + wn * 64 + fn * 16 + (lane & 15);
        float bv = bias[col];
        #pragma unroll
        for (int fm = 0; fm < 8; ++fm) {
            int row = m0 + wm * 128 + fm * 16 + (lane >> 4) * 4;
            #pragma unroll
            for (int v = 0; v < 4; ++v)
                out[(size_t)(row + v) * DOUT + col] = acc[fm][fn][v] + bv;
        }
    }
}

// ---------------------------------------------------------------------------
// Workspace (bytes):
//   xb   @ 0         : 33,554,432   (8192x2048 bf16)
//   Wb   @ 33554432  :  8,388,608   (2048x2048 bf16, shared LoRA folded)
//   pt   @ 41943040  :  8,388,608   (8x8192x64 bf16)
//   caug @ 50331648  :    262,144   (2048x64 bf16)
//   plog @ 50593792  :     16,384   (512x8 f32, fully overwritten)
// ---------------------------------------------------------------------------
extern "C" void kernel_launch(void* const* d_in, const int* in_sizes, int n_in,
                              void* d_out, int out_size, void* d_ws, size_t ws_size,
                              hipStream_t stream)
{
    const float* x        = (const float*)d_in[0];
    const float* base_W   = (const float*)d_in[1];
    const float* base_b   = (const float*)d_in[2];
    const float* shared_A = (const float*)d_in[3];
    const float* shared_B = (const float*)d_in[4];
    const float* expert_A = (const float*)d_in[5];
    const float* expert_B = (const float*)d_in[6];
    const float* task_emb = (const float*)d_in[7];
    const float* collab_w = (const float*)d_in[8];
    float* out = (float*)d_out;

    char* ws = (char*)d_ws;
    __bf16* xb   = (__bf16*)(ws + 0);
    __bf16* Wb   = (__bf16*)(ws + 33554432);
    __bf16* pt   = (__bf16*)(ws + 41943040);
    __bf16* caug = (__bf16*)(ws + 50331648);
    float*  plog = (float*) (ws + 50593792);

    mega_prep<<<dim3(4736), 256, 0, stream>>>(x, base_W, expert_A, shared_A,
                                              expert_B, shared_B, task_emb, collab_w,
                                              xb, Wb, caug, pt, plog);
    gemm_main<<<dim3(256), 512, 0, stream>>>(xb, Wb, pt, caug, plog, base_b, out);
}

// Round 6
// 231.883 us; speedup vs baseline: 1.0249x; 1.0093x over previous
//
#include <hip/hip_runtime.h>
#include <hip/hip_bf16.h>
#include <math.h>

// COLoRALinear: B=4, S=2048, D_IN=D_OUT=2048, E=8, R=8, SCALING=2.0
#define BATCH 4
#define SEQ   2048
#define DIN   2048
#define DOUT  2048
#define NEXP  8
#define RANK  8
#define MTOT  (BATCH * SEQ)   // 8192
#define KE    64              // expert aug rank (shared LoRA folded into Wb)
#define NKC   8               // split-K chunks in gemm_t

typedef __bf16 bf16x8 __attribute__((ext_vector_type(8)));
typedef __bf16 bf16x4 __attribute__((ext_vector_type(4)));
typedef float  f32x4  __attribute__((ext_vector_type(4)));

#define GLOBAL_AS __attribute__((address_space(1)))
#define LDS_AS    __attribute__((address_space(3)))

// Barrier fused with a compiler memory fence (no op can slip between them).
#define BARRIER() asm volatile("s_barrier" ::: "memory")

// ---------------------------------------------------------------------------
// K1 mega_prep (unchanged, passed rounds 0/2/5): 4736 blocks.
// ---------------------------------------------------------------------------
__global__ __launch_bounds__(256) void mega_prep(
    const float* __restrict__ x, const float* __restrict__ W,
    const float* __restrict__ expert_A, const float* __restrict__ shared_A,
    const float* __restrict__ expert_B, const float* __restrict__ shared_B,
    const float* __restrict__ task_emb, const float* __restrict__ collab,
    __bf16* __restrict__ xb, __bf16* __restrict__ Wb,
    __bf16* __restrict__ caug, __bf16* __restrict__ pt, float* __restrict__ plog)
{
    const int bid = blockIdx.x;
    const int t = threadIdx.x;

    if (bid >= 512) {
        if (bid < 4608) {
            size_t idx = ((size_t)(bid - 512) * 256 + t) * 4;
            int o = (int)(idx >> 11), i = (int)(idx & 2047);
            float cw = 1.0f / (1.0f + expf(-collab[0]));
            float s = cw * 2.0f;
            float4 w = *(const float4*)&W[idx];
            float dx = 0.f, dy = 0.f, dz = 0.f, dw = 0.f;
            #pragma unroll
            for (int r = 0; r < 8; ++r) {
                float bs = shared_B[(size_t)o * RANK + r];
                float4 as = *(const float4*)&shared_A[(size_t)r * DIN + i];
                dx += bs * as.x; dy += bs * as.y; dz += bs * as.z; dw += bs * as.w;
            }
            bf16x4 h = { (__bf16)(w.x + s * dx), (__bf16)(w.y + s * dy),
                         (__bf16)(w.z + s * dz), (__bf16)(w.w + s * dw) };
            *(bf16x4*)&Wb[idx] = h;
        } else {
            int idx = ((bid - 4608) * 256 + t) * 4;   // over 2048*64
            int o = idx >> 6, k = idx & 63;           // k multiple of 4
            float cw = 1.0f / (1.0f + expf(-collab[0]));
            float s = (1.0f - cw) * 2.0f;
            float4 v = *(const float4*)&expert_B[((size_t)(k >> 3) * DOUT + o) * RANK + (k & 7)];
            bf16x4 h = { (__bf16)(s * v.x), (__bf16)(s * v.y),
                         (__bf16)(s * v.z), (__bf16)(s * v.w) };
            *(bf16x4*)&caug[idx] = h;
        }
        return;
    }

    // ---- gemm_t tile ----
    __shared__ __bf16 lsA[128 * 64];
    __shared__ __bf16 lsB[96 * 64];
    __shared__ float lsc[32];
    const int lane = t & 63;
    const int w = t >> 6;
    const int kc = bid & 7;
    const int m0 = (bid >> 3) * 128;

    f32x4 acc[2][5];
    #pragma unroll
    for (int a = 0; a < 2; ++a)
        #pragma unroll
        for (int c = 0; c < 5; ++c) acc[a][c] = (f32x4){0.f, 0.f, 0.f, 0.f};

    for (int it = 0; it < 4; ++it) {
        int k0 = kc * 256 + it * 64;
        #pragma unroll
        for (int q = 0; q < 4; ++q) {
            int row = q * 32 + (t >> 3), sl = t & 7, seg = sl ^ (row & 7);
            const float* gp = x + (size_t)(m0 + row) * DIN + k0 + seg * 8;
            float4 v0 = *(const float4*)gp;
            float4 v1 = *(const float4*)(gp + 4);
            bf16x8 h = { (__bf16)v0.x, (__bf16)v0.y, (__bf16)v0.z, (__bf16)v0.w,
                         (__bf16)v1.x, (__bf16)v1.y, (__bf16)v1.z, (__bf16)v1.w };
            *(bf16x8*)&lsA[row * 64 + sl * 8] = h;
            *(bf16x8*)&xb[(size_t)(m0 + row) * DIN + k0 + seg * 8] = h;
        }
        #pragma unroll
        for (int q = 0; q < 3; ++q) {
            int c = q * 256 + t;
            int row = c >> 3, sl = c & 7, seg = sl ^ (row & 7);
            bf16x8 h = { (__bf16)0.f, (__bf16)0.f, (__bf16)0.f, (__bf16)0.f,
                         (__bf16)0.f, (__bf16)0.f, (__bf16)0.f, (__bf16)0.f };
            if (row < 64) {
                const float* gp = expert_A + (size_t)row * DIN + k0 + seg * 8;
                float4 v0 = *(const float4*)gp, v1 = *(const float4*)(gp + 4);
                h = bf16x8{ (__bf16)v0.x, (__bf16)v0.y, (__bf16)v0.z, (__bf16)v0.w,
                            (__bf16)v1.x, (__bf16)v1.y, (__bf16)v1.z, (__bf16)v1.w };
            } else if (row < 72) {
                const float* gp = task_emb + (size_t)(row - 64) * DIN + k0 + seg * 8;
                float4 v0 = *(const float4*)gp, v1 = *(const float4*)(gp + 4);
                h = bf16x8{ (__bf16)v0.x, (__bf16)v0.y, (__bf16)v0.z, (__bf16)v0.w,
                            (__bf16)v1.x, (__bf16)v1.y, (__bf16)v1.z, (__bf16)v1.w };
            }
            *(bf16x8*)&lsB[row * 64 + sl * 8] = h;
        }
        __syncthreads();
        #pragma unroll
        for (int kk = 0; kk < 2; ++kk) {
            bf16x8 af[2], bfr[5];
            #pragma unroll
            for (int tm = 0; tm < 2; ++tm) {
                int r = w * 32 + tm * 16 + (lane & 15);
                int slot = (kk * 4 + (lane >> 4)) ^ (r & 7);
                af[tm] = *(const bf16x8*)&lsA[r * 64 + slot * 8];
            }
            #pragma unroll
            for (int tn = 0; tn < 5; ++tn) {
                int r = tn * 16 + (lane & 15);
                int slot = (kk * 4 + (lane >> 4)) ^ (r & 7);
                bfr[tn] = *(const bf16x8*)&lsB[r * 64 + slot * 8];
            }
            #pragma unroll
            for (int tm = 0; tm < 2; ++tm)
                #pragma unroll
                for (int tn = 0; tn < 5; ++tn)
                    acc[tm][tn] = __builtin_amdgcn_mfma_f32_16x16x32_bf16(
                        af[tm], bfr[tn], acc[tm][tn], 0, 0, 0);
        }
        __syncthreads();
    }

    #pragma unroll
    for (int tm = 0; tm < 2; ++tm)
        #pragma unroll
        for (int tn = 0; tn < 4; ++tn) {
            int col = tn * 16 + (lane & 15);
            #pragma unroll
            for (int v = 0; v < 4; ++v) {
                int row = m0 + w * 32 + tm * 16 + (lane >> 4) * 4 + v;
                pt[((size_t)kc * MTOT + row) * KE + col] = (__bf16)acc[tm][tn][v];
            }
        }

    float s = 0.f;
    #pragma unroll
    for (int tm = 0; tm < 2; ++tm)
        #pragma unroll
        for (int v = 0; v < 4; ++v) s += acc[tm][4][v];
    s += __shfl_down(s, 32);
    s += __shfl_down(s, 16);
    if (lane < 8) lsc[w * 8 + lane] = s;
    __syncthreads();
    if (t < 8)
        plog[bid * 8 + t] = lsc[t] + lsc[8 + t] + lsc[16 + t] + lsc[24 + t];
}

// ---------------------------------------------------------------------------
// K2 gemm_main: ROUND-5 PASSING SKELETON + T4 counted vmcnt (only change).
// The 8 prefetch loads of a tile split by first-read time:
//   g1(j) = all 4 B q-chunks + A q0,q2 (rows read in phases 0-1)   [6 loads]
//   g2(j) = A q1,q3            (rows read in phases 2-3)           [2 loads]
// Issue timing: g2(j+1) at phase 0 of j; g1(j+2) at phase 2 of j.
// Waits: end of phase 1: vmcnt(8) retires g2(j)   (outstanding 10 -> 8)
//        end of phase 3: vmcnt(8) retires g1(j+1) (outstanding 14 -> 8)
// -> NEVER vmcnt(0) in steady state; waited loads issued 4-6 phases earlier;
//    8 loads stay in flight across every barrier (T4, m218: +38-73%).
// Ledger (verified): prologue g1(0),g2(0),g1(1)=14, vmcnt(8) retires g1(0).
// Tail: j=30 B2_3 vmcnt(2) retires g1(31); j=31 B2_1 vmcnt(0) retires g2(31).
// WAR: g1(j+2) overwrites B(j)/A-even(j), last consumed before B2_1 of j
// (issue is after it); g2(j+1) overwrites A-odd(j-1), consumed before
// B2_3 of j-1 (issue after it). All barriers fused asm (fence+barrier).
// Layout/swizzle/grid/correction identical to the round-5 passing kernel.
// ---------------------------------------------------------------------------
#define ISSUE_G1(j) do {                                                      \
    const int nb_ = ((j) & 1) * 16384;                                        \
    const __bf16* a_ = gA + (j) * 64;                                         \
    const __bf16* b_ = gB + (j) * 64;                                         \
    __builtin_amdgcn_global_load_lds((GLOBAL_AS void*)(b_ + 0 * 64 * DIN),    \
        (LDS_AS void*)&lds[32768 + nb_ + 0 * 4096 + lbase], 16, 0, 0);        \
    __builtin_amdgcn_global_load_lds((GLOBAL_AS void*)(b_ + 1 * 64 * DIN),    \
        (LDS_AS void*)&lds[32768 + nb_ + 1 * 4096 + lbase], 16, 0, 0);        \
    __builtin_amdgcn_global_load_lds((GLOBAL_AS void*)(b_ + 2 * 64 * DIN),    \
        (LDS_AS void*)&lds[32768 + nb_ + 2 * 4096 + lbase], 16, 0, 0);        \
    __builtin_amdgcn_global_load_lds((GLOBAL_AS void*)(b_ + 3 * 64 * DIN),    \
        (LDS_AS void*)&lds[32768 + nb_ + 3 * 4096 + lbase], 16, 0, 0);        \
    __builtin_amdgcn_global_load_lds((GLOBAL_AS void*)(a_ + 0 * 64 * DIN),    \
        (LDS_AS void*)&lds[nb_ + 0 * 4096 + lbase], 16, 0, 0);                \
    __builtin_amdgcn_global_load_lds((GLOBAL_AS void*)(a_ + 2 * 64 * DIN),    \
        (LDS_AS void*)&lds[nb_ + 2 * 4096 + lbase], 16, 0, 0);                \
} while (0)

#define ISSUE_G2(j) do {                                                      \
    const int nb_ = ((j) & 1) * 16384;                                        \
    const __bf16* a_ = gA + (j) * 64;                                         \
    __builtin_amdgcn_global_load_lds((GLOBAL_AS void*)(a_ + 1 * 64 * DIN),    \
        (LDS_AS void*)&lds[nb_ + 1 * 4096 + lbase], 16, 0, 0);                \
    __builtin_amdgcn_global_load_lds((GLOBAL_AS void*)(a_ + 3 * 64 * DIN),    \
        (LDS_AS void*)&lds[nb_ + 3 * 4096 + lbase], 16, 0, 0);                \
} while (0)

__global__ __launch_bounds__(512, 2) void gemm_main(
    const __bf16* __restrict__ xb, const __bf16* __restrict__ Wb,
    const __bf16* __restrict__ pt, const __bf16* __restrict__ caug,
    const float* __restrict__ plog, const float* __restrict__ bias,
    float* __restrict__ out)
{
    __shared__ __bf16 lds[65536];   // 128 KiB: elements [A0|A1|B0|B1] 16K each
    const int t = threadIdx.x;
    const int lane = t & 63;
    const int wid = t >> 6;
    const int wm = wid >> 2, wn = wid & 3;      // 2x4 wave grid, 128x64 per wave
    const int bid = blockIdx.x;
    const int xcd = bid & 7, j = bid >> 3;
    const int m0 = (xcd * 4 + (j >> 3)) * 256;  // 4 m-tiles per XCD
    const int n0 = (j & 7) * 256;               // all 8 n-tiles per XCD
    const int b  = m0 >> 11;

    // staging addressing (pre-swizzled source -> linear LDS fill)
    const int srow = t >> 3;                    // 0..63
    const int sseg = (t & 7) ^ (srow & 7);
    const __bf16* gA = xb + (size_t)(m0 + srow) * DIN + sseg * 8;
    const __bf16* gB = Wb + (size_t)(n0 + srow) * DIN + sseg * 8;
    const int lbase = (t & ~63) * 8;            // wave-uniform LDS element base

    // fragment ds_read offsets (^32 flips slot bit2: other K-half)
    int aoff[8], boff[4];
    #pragma unroll
    for (int fm = 0; fm < 8; ++fm) {
        int r = wm * 128 + fm * 16 + (lane & 15);
        aoff[fm] = r * 64 + (((lane >> 4) ^ (r & 7)) * 8);
    }
    #pragma unroll
    for (int fn = 0; fn < 4; ++fn) {
        int r = wn * 64 + fn * 16 + (lane & 15);
        boff[fn] = r * 64 + (((lane >> 4) ^ (r & 7)) * 8);
    }

    f32x4 acc[8][4];
    #pragma unroll
    for (int i = 0; i < 8; ++i)
        #pragma unroll
        for (int jj = 0; jj < 4; ++jj) acc[i][jj] = (f32x4){0.f, 0.f, 0.f, 0.f};

    // prologue: g1(0)+g2(0)+g1(1) = 14 in flight; vmcnt(8) retires g1(0)
    ISSUE_G1(0); ISSUE_G2(0); ISSUE_G1(1);
    asm volatile("s_waitcnt vmcnt(8)" ::: "memory");
    BARRIER();

    // ---- main loop: K = 2048, 32 K-tiles of BK=64, 4 phases each ----
    for (int kt = 0; kt < 32; ++kt) {
        const int abase = (kt & 1) * 16384;
        const int bbase = 32768 + (kt & 1) * 16384;
        bf16x8 bfrag[4][2];
        bf16x8 afr[2][2];

        // -- phase 0: shadow {issue g2(kt+1); read all B + A fm0,1} --
        if (kt < 31) ISSUE_G2(kt + 1);
        #pragma unroll
        for (int fn = 0; fn < 4; ++fn) {
            bfrag[fn][0] = *(const bf16x8*)&lds[bbase + boff[fn]];
            bfrag[fn][1] = *(const bf16x8*)&lds[bbase + (boff[fn] ^ 32)];
        }
        #pragma unroll
        for (int i = 0; i < 2; ++i) {
            afr[i][0] = *(const bf16x8*)&lds[abase + aoff[i]];
            afr[i][1] = *(const bf16x8*)&lds[abase + (aoff[i] ^ 32)];
        }
        BARRIER();                                  // B1_0
        __builtin_amdgcn_s_setprio(1);
        #pragma unroll
        for (int kk = 0; kk < 2; ++kk)
            #pragma unroll
            for (int i = 0; i < 2; ++i)
                #pragma unroll
                for (int fn = 0; fn < 4; ++fn)
                    acc[i][fn] = __builtin_amdgcn_mfma_f32_16x16x32_bf16(
                        afr[i][kk], bfrag[fn][kk], acc[i][fn], 0, 0, 0);
        __builtin_amdgcn_s_setprio(0);
        BARRIER();                                  // B2_0

        // -- phase 1: shadow {read A fm2,3} ; wait retires g2(kt) --
        #pragma unroll
        for (int i = 0; i < 2; ++i) {
            afr[i][0] = *(const bf16x8*)&lds[abase + aoff[2 + i]];
            afr[i][1] = *(const bf16x8*)&lds[abase + (aoff[2 + i] ^ 32)];
        }
        BARRIER();                                  // B1_1
        __builtin_amdgcn_s_setprio(1);
        #pragma unroll
        for (int kk = 0; kk < 2; ++kk)
            #pragma unroll
            for (int i = 0; i < 2; ++i)
                #pragma unroll
                for (int fn = 0; fn < 4; ++fn)
                    acc[2 + i][fn] = __builtin_amdgcn_mfma_f32_16x16x32_bf16(
                        afr[i][kk], bfrag[fn][kk], acc[2 + i][fn], 0, 0, 0);
        __builtin_amdgcn_s_setprio(0);
        if (kt < 31) asm volatile("s_waitcnt vmcnt(8)" ::: "memory");
        else         asm volatile("s_waitcnt vmcnt(0)" ::: "memory");
        BARRIER();                                  // B2_1

        // -- phase 2: shadow {issue g1(kt+2); read A fm4,5} --
        if (kt < 30) ISSUE_G1(kt + 2);
        #pragma unroll
        for (int i = 0; i < 2; ++i) {
            afr[i][0] = *(const bf16x8*)&lds[abase + aoff[4 + i]];
            afr[i][1] = *(const bf16x8*)&lds[abase + (aoff[4 + i] ^ 32)];
        }
        BARRIER();                                  // B1_2
        __builtin_amdgcn_s_setprio(1);
        #pragma unroll
        for (int kk = 0; kk < 2; ++kk)
            #pragma unroll
            for (int i = 0; i < 2; ++i)
                #pragma unroll
                for (int fn = 0; fn < 4; ++fn)
                    acc[4 + i][fn] = __builtin_amdgcn_mfma_f32_16x16x32_bf16(
                        afr[i][kk], bfrag[fn][kk], acc[4 + i][fn], 0, 0, 0);
        __builtin_amdgcn_s_setprio(0);
        BARRIER();                                  // B2_2

        // -- phase 3: shadow {read A fm6,7} ; wait retires g1(kt+1) --
        #pragma unroll
        for (int i = 0; i < 2; ++i) {
            afr[i][0] = *(const bf16x8*)&lds[abase + aoff[6 + i]];
            afr[i][1] = *(const bf16x8*)&lds[abase + (aoff[6 + i] ^ 32)];
        }
        BARRIER();                                  // B1_3
        __builtin_amdgcn_s_setprio(1);
        #pragma unroll
        for (int kk = 0; kk < 2; ++kk)
            #pragma unroll
            for (int i = 0; i < 2; ++i)
                #pragma unroll
                for (int fn = 0; fn < 4; ++fn)
                    acc[6 + i][fn] = __builtin_amdgcn_mfma_f32_16x16x32_bf16(
                        afr[i][kk], bfrag[fn][kk], acc[6 + i][fn], 0, 0, 0);
        __builtin_amdgcn_s_setprio(0);
        if (kt < 30)       asm volatile("s_waitcnt vmcnt(8)" ::: "memory");
        else if (kt == 30) asm volatile("s_waitcnt vmcnt(2)" ::: "memory");
        BARRIER();                                  // B2_3
    }

    // ---- correction phase (LDS buffers now free; vmcnt==0 here) ----
    // (a) caug -> B0 region (DMA, drained before (d))
    {
        const __bf16* gC = caug + (size_t)(n0 + srow) * KE + sseg * 8;
        #pragma unroll
        for (int q = 0; q < 4; ++q)
            __builtin_amdgcn_global_load_lds((GLOBAL_AS void*)(gC + q * 64 * KE),
                (LDS_AS void*)&lds[32768 + q * 4096 + lbase], 16, 0, 0);
    }
    // (b) logits: sum plog[b*128 .. +128][8] -> softmax factors f[8]
    float* scr = (float*)&lds[16384];           // overlay on A1 (512 + 8 f32)
    float* lgs = scr + 512;
    {
        const float* pb = plog + (size_t)b * 128 * 8;
        int e = t & 7, rr = t >> 3;             // rr 0..63
        scr[rr * 8 + e] = pb[rr * 8 + e] + pb[(rr + 64) * 8 + e];
    }
    asm volatile("s_waitcnt lgkmcnt(0)" ::: "memory");
    BARRIER();
    if (t < 8) {
        float s = 0.f;
        #pragma unroll
        for (int i = 0; i < 64; ++i) s += scr[i * 8 + t];
        lgs[t] = s;
    }
    asm volatile("s_waitcnt lgkmcnt(0)" ::: "memory");
    BARRIER();
    float f[NEXP];
    {
        float li[NEXP];
        #pragma unroll
        for (int e = 0; e < NEXP; ++e) li[e] = lgs[e] * (1.0f / (float)SEQ);
        float mx = li[0];
        #pragma unroll
        for (int e = 1; e < NEXP; ++e) mx = fmaxf(mx, li[e]);
        float den = 0.f;
        #pragma unroll
        for (int e = 0; e < NEXP; ++e) { f[e] = expf(li[e] - mx); den += f[e]; }
        float rden = 1.0f / den;
        #pragma unroll
        for (int e = 0; e < NEXP; ++e) f[e] *= rden;
    }
    // (c) build scaled tb tile into A0 (swizzled layout the readers expect)
    #pragma unroll
    for (int q = 0; q < 4; ++q) {
        int row = q * 64 + srow;
        const __bf16* p0 = pt + (size_t)(m0 + row) * KE + sseg * 8;
        float sum[8] = {0.f, 0.f, 0.f, 0.f, 0.f, 0.f, 0.f, 0.f};
        #pragma unroll
        for (int kc = 0; kc < NKC; ++kc) {
            bf16x8 v = *(const bf16x8*)(p0 + (size_t)kc * MTOT * KE);
            #pragma unroll
            for (int jj = 0; jj < 8; ++jj) sum[jj] += (float)v[jj];
        }
        float fe = f[sseg];                     // chunk spans exactly one expert
        bf16x8 h;
        #pragma unroll
        for (int jj = 0; jj < 8; ++jj) h[jj] = (__bf16)(sum[jj] * fe);
        *(bf16x8*)&lds[row * 64 + (t & 7) * 8] = h;
    }
    asm volatile("s_waitcnt vmcnt(0) lgkmcnt(0)" ::: "memory");
    BARRIER();
    // (d) correction MFMAs (K=64)
    {
        bf16x8 bfrag[4][2];
        #pragma unroll
        for (int fn = 0; fn < 4; ++fn) {
            bfrag[fn][0] = *(const bf16x8*)&lds[32768 + boff[fn]];
            bfrag[fn][1] = *(const bf16x8*)&lds[32768 + (boff[fn] ^ 32)];
        }
        #pragma unroll
        for (int fm = 0; fm < 8; ++fm) {
            bf16x8 a0 = *(const bf16x8*)&lds[aoff[fm]];
            bf16x8 a1 = *(const bf16x8*)&lds[aoff[fm] ^ 32];
            #pragma unroll
            for (int fn = 0; fn < 4; ++fn) {
                acc[fm][fn] = __builtin_amdgcn_mfma_f32_16x16x32_bf16(
                    a0, bfrag[fn][0], acc[fm][fn], 0, 0, 0);
                acc[fm][fn] = __builtin_amdgcn_mfma_f32_16x16x32_bf16(
                    a1, bfrag[fn][1], acc[fm][fn], 0, 0, 0);
            }
        }
    }

    // ---- epilogue: bias + fp32 store ----
    #pragma unroll
    for (int fn = 0; fn < 4; ++fn) {
        int col = n0 + wn * 64 + fn * 16 + (lane & 15);
        float bv = bias[col];
        #pragma unroll
        for (int fm = 0; fm < 8; ++fm) {
            int row = m0 + wm * 128 + fm * 16 + (lane >> 4) * 4;
            #pragma unroll
            for (int v = 0; v < 4; ++v)
                out[(size_t)(row + v) * DOUT + col] = acc[fm][fn][v] + bv;
        }
    }
}

// ---------------------------------------------------------------------------
// Workspace (bytes):
//   xb   @ 0         : 33,554,432   (8192x2048 bf16)
//   Wb   @ 33554432  :  8,388,608   (2048x2048 bf16, shared LoRA folded)
//   pt   @ 41943040  :  8,388,608   (8x8192x64 bf16)
//   caug @ 50331648  :    262,144   (2048x64 bf16)
//   plog @ 50593792  :     16,384   (512x8 f32, fully overwritten)
// ---------------------------------------------------------------------------
extern "C" void kernel_launch(void* const* d_in, const int* in_sizes, int n_in,
                              void* d_out, int out_size, void* d_ws, size_t ws_size,
                              hipStream_t stream)
{
    const float* x        = (const float*)d_in[0];
    const float* base_W   = (const float*)d_in[1];
    const float* base_b   = (const float*)d_in[2];
    const float* shared_A = (const float*)d_in[3];
    const float* shared_B = (const float*)d_in[4];
    const float* expert_A = (const float*)d_in[5];
    const float* expert_B = (const float*)d_in[6];
    const float* task_emb = (const float*)d_in[7];
    const float* collab_w = (const float*)d_in[8];
    float* out = (float*)d_out;

    char* ws = (char*)d_ws;
    __bf16* xb   = (__bf16*)(ws + 0);
    __bf16* Wb   = (__bf16*)(ws + 33554432);
    __bf16* pt   = (__bf16*)(ws + 41943040);
    __bf16* caug = (__bf16*)(ws + 50331648);
    float*  plog = (float*) (ws + 50593792);

    mega_prep<<<dim3(4736), 256, 0, stream>>>(x, base_W, expert_A, shared_A,
                                              expert_B, shared_B, task_emb, collab_w,
                                              xb, Wb, caug, pt, plog);
    gemm_main<<<dim3(256), 512, 0, stream>>>(xb, Wb, pt, caug, plog, base_b, out);
}

// Round 7
// 230.248 us; speedup vs baseline: 1.0322x; 1.0071x over previous
//
#include <hip/hip_runtime.h>
#include <hip/hip_bf16.h>
#include <math.h>

// COLoRALinear: B=4, S=2048, D_IN=D_OUT=2048, E=8, R=8, SCALING=2.0
#define BATCH 4
#define SEQ   2048
#define DIN   2048
#define DOUT  2048
#define NEXP  8
#define RANK  8
#define MTOT  (BATCH * SEQ)   // 8192
#define KE    64              // expert aug rank (shared LoRA folded into Wb)
#define NKC   8               // split-K chunks in gemm_t

typedef __bf16 bf16x8 __attribute__((ext_vector_type(8)));
typedef __bf16 bf16x4 __attribute__((ext_vector_type(4)));
typedef float  f32x4  __attribute__((ext_vector_type(4)));

#define GLOBAL_AS __attribute__((address_space(1)))
#define LDS_AS    __attribute__((address_space(3)))

// Barrier fused with a compiler memory fence (no op can slip between them).
#define BARRIER() asm volatile("s_barrier" ::: "memory")

// ---------------------------------------------------------------------------
// K1 mega_prep (unchanged, passed rounds 0/2/5/6): 4736 blocks.
// ---------------------------------------------------------------------------
__global__ __launch_bounds__(256) void mega_prep(
    const float* __restrict__ x, const float* __restrict__ W,
    const float* __restrict__ expert_A, const float* __restrict__ shared_A,
    const float* __restrict__ expert_B, const float* __restrict__ shared_B,
    const float* __restrict__ task_emb, const float* __restrict__ collab,
    __bf16* __restrict__ xb, __bf16* __restrict__ Wb,
    __bf16* __restrict__ caug, __bf16* __restrict__ pt, float* __restrict__ plog)
{
    const int bid = blockIdx.x;
    const int t = threadIdx.x;

    if (bid >= 512) {
        if (bid < 4608) {
            size_t idx = ((size_t)(bid - 512) * 256 + t) * 4;
            int o = (int)(idx >> 11), i = (int)(idx & 2047);
            float cw = 1.0f / (1.0f + expf(-collab[0]));
            float s = cw * 2.0f;
            float4 w = *(const float4*)&W[idx];
            float dx = 0.f, dy = 0.f, dz = 0.f, dw = 0.f;
            #pragma unroll
            for (int r = 0; r < 8; ++r) {
                float bs = shared_B[(size_t)o * RANK + r];
                float4 as = *(const float4*)&shared_A[(size_t)r * DIN + i];
                dx += bs * as.x; dy += bs * as.y; dz += bs * as.z; dw += bs * as.w;
            }
            bf16x4 h = { (__bf16)(w.x + s * dx), (__bf16)(w.y + s * dy),
                         (__bf16)(w.z + s * dz), (__bf16)(w.w + s * dw) };
            *(bf16x4*)&Wb[idx] = h;
        } else {
            int idx = ((bid - 4608) * 256 + t) * 4;   // over 2048*64
            int o = idx >> 6, k = idx & 63;           // k multiple of 4
            float cw = 1.0f / (1.0f + expf(-collab[0]));
            float s = (1.0f - cw) * 2.0f;
            float4 v = *(const float4*)&expert_B[((size_t)(k >> 3) * DOUT + o) * RANK + (k & 7)];
            bf16x4 h = { (__bf16)(s * v.x), (__bf16)(s * v.y),
                         (__bf16)(s * v.z), (__bf16)(s * v.w) };
            *(bf16x4*)&caug[idx] = h;
        }
        return;
    }

    // ---- gemm_t tile ----
    __shared__ __bf16 lsA[128 * 64];
    __shared__ __bf16 lsB[96 * 64];
    __shared__ float lsc[32];
    const int lane = t & 63;
    const int w = t >> 6;
    const int kc = bid & 7;
    const int m0 = (bid >> 3) * 128;

    f32x4 acc[2][5];
    #pragma unroll
    for (int a = 0; a < 2; ++a)
        #pragma unroll
        for (int c = 0; c < 5; ++c) acc[a][c] = (f32x4){0.f, 0.f, 0.f, 0.f};

    for (int it = 0; it < 4; ++it) {
        int k0 = kc * 256 + it * 64;
        #pragma unroll
        for (int q = 0; q < 4; ++q) {
            int row = q * 32 + (t >> 3), sl = t & 7, seg = sl ^ (row & 7);
            const float* gp = x + (size_t)(m0 + row) * DIN + k0 + seg * 8;
            float4 v0 = *(const float4*)gp;
            float4 v1 = *(const float4*)(gp + 4);
            bf16x8 h = { (__bf16)v0.x, (__bf16)v0.y, (__bf16)v0.z, (__bf16)v0.w,
                         (__bf16)v1.x, (__bf16)v1.y, (__bf16)v1.z, (__bf16)v1.w };
            *(bf16x8*)&lsA[row * 64 + sl * 8] = h;
            *(bf16x8*)&xb[(size_t)(m0 + row) * DIN + k0 + seg * 8] = h;
        }
        #pragma unroll
        for (int q = 0; q < 3; ++q) {
            int c = q * 256 + t;
            int row = c >> 3, sl = c & 7, seg = sl ^ (row & 7);
            bf16x8 h = { (__bf16)0.f, (__bf16)0.f, (__bf16)0.f, (__bf16)0.f,
                         (__bf16)0.f, (__bf16)0.f, (__bf16)0.f, (__bf16)0.f };
            if (row < 64) {
                const float* gp = expert_A + (size_t)row * DIN + k0 + seg * 8;
                float4 v0 = *(const float4*)gp, v1 = *(const float4*)(gp + 4);
                h = bf16x8{ (__bf16)v0.x, (__bf16)v0.y, (__bf16)v0.z, (__bf16)v0.w,
                            (__bf16)v1.x, (__bf16)v1.y, (__bf16)v1.z, (__bf16)v1.w };
            } else if (row < 72) {
                const float* gp = task_emb + (size_t)(row - 64) * DIN + k0 + seg * 8;
                float4 v0 = *(const float4*)gp, v1 = *(const float4*)(gp + 4);
                h = bf16x8{ (__bf16)v0.x, (__bf16)v0.y, (__bf16)v0.z, (__bf16)v0.w,
                            (__bf16)v1.x, (__bf16)v1.y, (__bf16)v1.z, (__bf16)v1.w };
            }
            *(bf16x8*)&lsB[row * 64 + sl * 8] = h;
        }
        __syncthreads();
        #pragma unroll
        for (int kk = 0; kk < 2; ++kk) {
            bf16x8 af[2], bfr[5];
            #pragma unroll
            for (int tm = 0; tm < 2; ++tm) {
                int r = w * 32 + tm * 16 + (lane & 15);
                int slot = (kk * 4 + (lane >> 4)) ^ (r & 7);
                af[tm] = *(const bf16x8*)&lsA[r * 64 + slot * 8];
            }
            #pragma unroll
            for (int tn = 0; tn < 5; ++tn) {
                int r = tn * 16 + (lane & 15);
                int slot = (kk * 4 + (lane >> 4)) ^ (r & 7);
                bfr[tn] = *(const bf16x8*)&lsB[r * 64 + slot * 8];
            }
            #pragma unroll
            for (int tm = 0; tm < 2; ++tm)
                #pragma unroll
                for (int tn = 0; tn < 5; ++tn)
                    acc[tm][tn] = __builtin_amdgcn_mfma_f32_16x16x32_bf16(
                        af[tm], bfr[tn], acc[tm][tn], 0, 0, 0);
        }
        __syncthreads();
    }

    #pragma unroll
    for (int tm = 0; tm < 2; ++tm)
        #pragma unroll
        for (int tn = 0; tn < 4; ++tn) {
            int col = tn * 16 + (lane & 15);
            #pragma unroll
            for (int v = 0; v < 4; ++v) {
                int row = m0 + w * 32 + tm * 16 + (lane >> 4) * 4 + v;
                pt[((size_t)kc * MTOT + row) * KE + col] = (__bf16)acc[tm][tn][v];
            }
        }

    float s = 0.f;
    #pragma unroll
    for (int tm = 0; tm < 2; ++tm)
        #pragma unroll
        for (int v = 0; v < 4; ++v) s += acc[tm][4][v];
    s += __shfl_down(s, 32);
    s += __shfl_down(s, 16);
    if (lane < 8) lsc[w * 8 + lane] = s;
    __syncthreads();
    if (t < 8)
        plog[bid * 8 + t] = lsc[t] + lsc[8 + t] + lsc[16 + t] + lsc[24 + t];
}

// ---------------------------------------------------------------------------
// K2 gemm_main: ROUND-6 PASSING SKELETON with phase granularity halved:
// 2 phases per K-tile (32 MFMA each) -> 4 barriers/tile instead of 8.
// A/B vs round 6 isolates barrier-region count (the theorized residual:
// ds_read and MFMA regions are barrier-serialized, so per-region fixed
// overhead x region count dominates at 2 waves/SIMD).
// Load groups unchanged: g1(j) = B(4) + A q0,q2 (6 loads, feeds P0 fm0-3);
// g2(j) = A q1,q3 (2 loads, feeds P1 fm4-7).
// Issue: g2(kt+1) in P0 shadow; g1(kt+2) in P1 shadow.
// Ledger (traced): prologue g1(0),g2(0),g1(1)=14 -> vmcnt(8) retires g1(0).
// Steady: P0 +2 -> 10, wait vmcnt(8) retires g2(kt); P1 +6 -> 14, wait
// vmcnt(8) retires g1(kt+1). NEVER 0 until tail: kt=30 P1 vmcnt(2) retires
// g1(31); kt=31 P0 vmcnt(0) retires g2(31). WAR: DMA issue points sit after
// the barrier that proves all waves consumed the overwritten region (same
// topology as round 6). All barriers fused asm (fence+barrier).
// ---------------------------------------------------------------------------
#define ISSUE_G1(j) do {                                                      \
    const int nb_ = ((j) & 1) * 16384;                                        \
    const __bf16* a_ = gA + (j) * 64;                                         \
    const __bf16* b_ = gB + (j) * 64;                                         \
    __builtin_amdgcn_global_load_lds((GLOBAL_AS void*)(b_ + 0 * 64 * DIN),    \
        (LDS_AS void*)&lds[32768 + nb_ + 0 * 4096 + lbase], 16, 0, 0);        \
    __builtin_amdgcn_global_load_lds((GLOBAL_AS void*)(b_ + 1 * 64 * DIN),    \
        (LDS_AS void*)&lds[32768 + nb_ + 1 * 4096 + lbase], 16, 0, 0);        \
    __builtin_amdgcn_global_load_lds((GLOBAL_AS void*)(b_ + 2 * 64 * DIN),    \
        (LDS_AS void*)&lds[32768 + nb_ + 2 * 4096 + lbase], 16, 0, 0);        \
    __builtin_amdgcn_global_load_lds((GLOBAL_AS void*)(b_ + 3 * 64 * DIN),    \
        (LDS_AS void*)&lds[32768 + nb_ + 3 * 4096 + lbase], 16, 0, 0);        \
    __builtin_amdgcn_global_load_lds((GLOBAL_AS void*)(a_ + 0 * 64 * DIN),    \
        (LDS_AS void*)&lds[nb_ + 0 * 4096 + lbase], 16, 0, 0);                \
    __builtin_amdgcn_global_load_lds((GLOBAL_AS void*)(a_ + 2 * 64 * DIN),    \
        (LDS_AS void*)&lds[nb_ + 2 * 4096 + lbase], 16, 0, 0);                \
} while (0)

#define ISSUE_G2(j) do {                                                      \
    const int nb_ = ((j) & 1) * 16384;                                        \
    const __bf16* a_ = gA + (j) * 64;                                         \
    __builtin_amdgcn_global_load_lds((GLOBAL_AS void*)(a_ + 1 * 64 * DIN),    \
        (LDS_AS void*)&lds[nb_ + 1 * 4096 + lbase], 16, 0, 0);                \
    __builtin_amdgcn_global_load_lds((GLOBAL_AS void*)(a_ + 3 * 64 * DIN),    \
        (LDS_AS void*)&lds[nb_ + 3 * 4096 + lbase], 16, 0, 0);                \
} while (0)

__global__ __launch_bounds__(512, 2) void gemm_main(
    const __bf16* __restrict__ xb, const __bf16* __restrict__ Wb,
    const __bf16* __restrict__ pt, const __bf16* __restrict__ caug,
    const float* __restrict__ plog, const float* __restrict__ bias,
    float* __restrict__ out)
{
    __shared__ __bf16 lds[65536];   // 128 KiB: elements [A0|A1|B0|B1] 16K each
    const int t = threadIdx.x;
    const int lane = t & 63;
    const int wid = t >> 6;
    const int wm = wid >> 2, wn = wid & 3;      // 2x4 wave grid, 128x64 per wave
    const int bid = blockIdx.x;
    const int xcd = bid & 7, j = bid >> 3;
    const int m0 = (xcd * 4 + (j >> 3)) * 256;  // 4 m-tiles per XCD
    const int n0 = (j & 7) * 256;               // all 8 n-tiles per XCD
    const int b  = m0 >> 11;

    // staging addressing (pre-swizzled source -> linear LDS fill)
    const int srow = t >> 3;                    // 0..63
    const int sseg = (t & 7) ^ (srow & 7);
    const __bf16* gA = xb + (size_t)(m0 + srow) * DIN + sseg * 8;
    const __bf16* gB = Wb + (size_t)(n0 + srow) * DIN + sseg * 8;
    const int lbase = (t & ~63) * 8;            // wave-uniform LDS element base

    // fragment ds_read offsets (^32 flips slot bit2: other K-half)
    int aoff[8], boff[4];
    #pragma unroll
    for (int fm = 0; fm < 8; ++fm) {
        int r = wm * 128 + fm * 16 + (lane & 15);
        aoff[fm] = r * 64 + (((lane >> 4) ^ (r & 7)) * 8);
    }
    #pragma unroll
    for (int fn = 0; fn < 4; ++fn) {
        int r = wn * 64 + fn * 16 + (lane & 15);
        boff[fn] = r * 64 + (((lane >> 4) ^ (r & 7)) * 8);
    }

    f32x4 acc[8][4];
    #pragma unroll
    for (int i = 0; i < 8; ++i)
        #pragma unroll
        for (int jj = 0; jj < 4; ++jj) acc[i][jj] = (f32x4){0.f, 0.f, 0.f, 0.f};

    // prologue: g1(0)+g2(0)+g1(1) = 14 in flight; vmcnt(8) retires g1(0)
    ISSUE_G1(0); ISSUE_G2(0); ISSUE_G1(1);
    asm volatile("s_waitcnt vmcnt(8)" ::: "memory");
    BARRIER();

    // ---- main loop: K = 2048, 32 K-tiles of BK=64, 2 phases each ----
    for (int kt = 0; kt < 32; ++kt) {
        const int abase = (kt & 1) * 16384;
        const int bbase = 32768 + (kt & 1) * 16384;
        bf16x8 bfrag[4][2];
        bf16x8 afr[4][2];

        // -- P0: shadow {issue g2(kt+1); read B all + A fm0-3} ; MFMA fm0-3 --
        if (kt < 31) ISSUE_G2(kt + 1);
        #pragma unroll
        for (int fn = 0; fn < 4; ++fn) {
            bfrag[fn][0] = *(const bf16x8*)&lds[bbase + boff[fn]];
            bfrag[fn][1] = *(const bf16x8*)&lds[bbase + (boff[fn] ^ 32)];
        }
        #pragma unroll
        for (int i = 0; i < 4; ++i) {
            afr[i][0] = *(const bf16x8*)&lds[abase + aoff[i]];
            afr[i][1] = *(const bf16x8*)&lds[abase + (aoff[i] ^ 32)];
        }
        BARRIER();                                  // B1_P0
        __builtin_amdgcn_s_setprio(1);
        #pragma unroll
        for (int kk = 0; kk < 2; ++kk)
            #pragma unroll
            for (int i = 0; i < 4; ++i)
                #pragma unroll
                for (int fn = 0; fn < 4; ++fn)
                    acc[i][fn] = __builtin_amdgcn_mfma_f32_16x16x32_bf16(
                        afr[i][kk], bfrag[fn][kk], acc[i][fn], 0, 0, 0);
        __builtin_amdgcn_s_setprio(0);
        if (kt < 31) asm volatile("s_waitcnt vmcnt(8)" ::: "memory");
        else         asm volatile("s_waitcnt vmcnt(0)" ::: "memory");
        BARRIER();                                  // B2_P0

        // -- P1: shadow {issue g1(kt+2); read A fm4-7} ; MFMA fm4-7 --
        if (kt < 30) ISSUE_G1(kt + 2);
        #pragma unroll
        for (int i = 0; i < 4; ++i) {
            afr[i][0] = *(const bf16x8*)&lds[abase + aoff[4 + i]];
            afr[i][1] = *(const bf16x8*)&lds[abase + (aoff[4 + i] ^ 32)];
        }
        BARRIER();                                  // B1_P1
        __builtin_amdgcn_s_setprio(1);
        #pragma unroll
        for (int kk = 0; kk < 2; ++kk)
            #pragma unroll
            for (int i = 0; i < 4; ++i)
                #pragma unroll
                for (int fn = 0; fn < 4; ++fn)
                    acc[4 + i][fn] = __builtin_amdgcn_mfma_f32_16x16x32_bf16(
                        afr[i][kk], bfrag[fn][kk], acc[4 + i][fn], 0, 0, 0);
        __builtin_amdgcn_s_setprio(0);
        if (kt < 30)       asm volatile("s_waitcnt vmcnt(8)" ::: "memory");
        else if (kt == 30) asm volatile("s_waitcnt vmcnt(2)" ::: "memory");
        BARRIER();                                  // B2_P1
    }

    // ---- correction phase (LDS buffers now free; vmcnt==0 here) ----
    // (a) caug -> B0 region (DMA, drained before (d))
    {
        const __bf16* gC = caug + (size_t)(n0 + srow) * KE + sseg * 8;
        #pragma unroll
        for (int q = 0; q < 4; ++q)
            __builtin_amdgcn_global_load_lds((GLOBAL_AS void*)(gC + q * 64 * KE),
                (LDS_AS void*)&lds[32768 + q * 4096 + lbase], 16, 0, 0);
    }
    // (b) logits: sum plog[b*128 .. +128][8] -> softmax factors f[8]
    float* scr = (float*)&lds[16384];           // overlay on A1 (512 + 8 f32)
    float* lgs = scr + 512;
    {
        const float* pb = plog + (size_t)b * 128 * 8;
        int e = t & 7, rr = t >> 3;             // rr 0..63
        scr[rr * 8 + e] = pb[rr * 8 + e] + pb[(rr + 64) * 8 + e];
    }
    asm volatile("s_waitcnt lgkmcnt(0)" ::: "memory");
    BARRIER();
    if (t < 8) {
        float s = 0.f;
        #pragma unroll
        for (int i = 0; i < 64; ++i) s += scr[i * 8 + t];
        lgs[t] = s;
    }
    asm volatile("s_waitcnt lgkmcnt(0)" ::: "memory");
    BARRIER();
    float f[NEXP];
    {
        float li[NEXP];
        #pragma unroll
        for (int e = 0; e < NEXP; ++e) li[e] = lgs[e] * (1.0f / (float)SEQ);
        float mx = li[0];
        #pragma unroll
        for (int e = 1; e < NEXP; ++e) mx = fmaxf(mx, li[e]);
        float den = 0.f;
        #pragma unroll
        for (int e = 0; e < NEXP; ++e) { f[e] = expf(li[e] - mx); den += f[e]; }
        float rden = 1.0f / den;
        #pragma unroll
        for (int e = 0; e < NEXP; ++e) f[e] *= rden;
    }
    // (c) build scaled tb tile into A0 (swizzled layout the readers expect)
    #pragma unroll
    for (int q = 0; q < 4; ++q) {
        int row = q * 64 + srow;
        const __bf16* p0 = pt + (size_t)(m0 + row) * KE + sseg * 8;
        float sum[8] = {0.f, 0.f, 0.f, 0.f, 0.f, 0.f, 0.f, 0.f};
        #pragma unroll
        for (int kc = 0; kc < NKC; ++kc) {
            bf16x8 v = *(const bf16x8*)(p0 + (size_t)kc * MTOT * KE);
            #pragma unroll
            for (int jj = 0; jj < 8; ++jj) sum[jj] += (float)v[jj];
        }
        float fe = f[sseg];                     // chunk spans exactly one expert
        bf16x8 h;
        #pragma unroll
        for (int jj = 0; jj < 8; ++jj) h[jj] = (__bf16)(sum[jj] * fe);
        *(bf16x8*)&lds[row * 64 + (t & 7) * 8] = h;
    }
    asm volatile("s_waitcnt vmcnt(0) lgkmcnt(0)" ::: "memory");
    BARRIER();
    // (d) correction MFMAs (K=64)
    {
        bf16x8 bfrag[4][2];
        #pragma unroll
        for (int fn = 0; fn < 4; ++fn) {
            bfrag[fn][0] = *(const bf16x8*)&lds[32768 + boff[fn]];
            bfrag[fn][1] = *(const bf16x8*)&lds[32768 + (boff[fn] ^ 32)];
        }
        #pragma unroll
        for (int fm = 0; fm < 8; ++fm) {
            bf16x8 a0 = *(const bf16x8*)&lds[aoff[fm]];
            bf16x8 a1 = *(const bf16x8*)&lds[aoff[fm] ^ 32];
            #pragma unroll
            for (int fn = 0; fn < 4; ++fn) {
                acc[fm][fn] = __builtin_amdgcn_mfma_f32_16x16x32_bf16(
                    a0, bfrag[fn][0], acc[fm][fn], 0, 0, 0);
                acc[fm][fn] = __builtin_amdgcn_mfma_f32_16x16x32_bf16(
                    a1, bfrag[fn][1], acc[fm][fn], 0, 0, 0);
            }
        }
    }

    // ---- epilogue: bias + fp32 store ----
    #pragma unroll
    for (int fn = 0; fn < 4; ++fn) {
        int col = n0 + wn * 64 + fn * 16 + (lane & 15);
        float bv = bias[col];
        #pragma unroll
        for (int fm = 0; fm < 8; ++fm) {
            int row = m0 + wm * 128 + fm * 16 + (lane >> 4) * 4;
            #pragma unroll
            for (int v = 0; v < 4; ++v)
                out[(size_t)(row + v) * DOUT + col] = acc[fm][fn][v] + bv;
        }
    }
}

// ---------------------------------------------------------------------------
// Workspace (bytes):
//   xb   @ 0         : 33,554,432   (8192x2048 bf16)
//   Wb   @ 33554432  :  8,388,608   (2048x2048 bf16, shared LoRA folded)
//   pt   @ 41943040  :  8,388,608   (8x8192x64 bf16)
//   caug @ 50331648  :    262,144   (2048x64 bf16)
//   plog @ 50593792  :     16,384   (512x8 f32, fully overwritten)
// ---------------------------------------------------------------------------
extern "C" void kernel_launch(void* const* d_in, const int* in_sizes, int n_in,
                              void* d_out, int out_size, void* d_ws, size_t ws_size,
                              hipStream_t stream)
{
    const float* x        = (const float*)d_in[0];
    const float* base_W   = (const float*)d_in[1];
    const float* base_b   = (const float*)d_in[2];
    const float* shared_A = (const float*)d_in[3];
    const float* shared_B = (const float*)d_in[4];
    const float* expert_A = (const float*)d_in[5];
    const float* expert_B = (const float*)d_in[6];
    const float* task_emb = (const float*)d_in[7];
    const float* collab_w = (const float*)d_in[8];
    float* out = (float*)d_out;

    char* ws = (char*)d_ws;
    __bf16* xb   = (__bf16*)(ws + 0);
    __bf16* Wb   = (__bf16*)(ws + 33554432);
    __bf16* pt   = (__bf16*)(ws + 41943040);
    __bf16* caug = (__bf16*)(ws + 50331648);
    float*  plog = (float*) (ws + 50593792);

    mega_prep<<<dim3(4736), 256, 0, stream>>>(x, base_W, expert_A, shared_A,
                                              expert_B, shared_B, task_emb, collab_w,
                                              xb, Wb, caug, pt, plog);
    gemm_main<<<dim3(256), 512, 0, stream>>>(xb, Wb, pt, caug, plog, base_b, out);
}

// Round 8
// 228.755 us; speedup vs baseline: 1.0389x; 1.0065x over previous
//
#include <hip/hip_runtime.h>
#include <hip/hip_bf16.h>
#include <math.h>

// COLoRALinear: B=4, S=2048, D_IN=D_OUT=2048, E=8, R=8, SCALING=2.0
#define BATCH 4
#define SEQ   2048
#define DIN   2048
#define DOUT  2048
#define NEXP  8
#define RANK  8
#define MTOT  (BATCH * SEQ)   // 8192
#define KE    64              // expert aug rank (shared LoRA folded into Wb)
#define NKC   8               // split-K chunks in gemm_t

typedef __bf16 bf16x8 __attribute__((ext_vector_type(8)));
typedef __bf16 bf16x4 __attribute__((ext_vector_type(4)));
typedef float  f32x4  __attribute__((ext_vector_type(4)));

#define GLOBAL_AS __attribute__((address_space(1)))
#define LDS_AS    __attribute__((address_space(3)))

// Barrier fused with a compiler memory fence (no op can slip between them).
#define BARRIER() asm volatile("s_barrier" ::: "memory")

// ---------------------------------------------------------------------------
// K1 mega_prep (unchanged, passed rounds 0/2/5/6/7): 4736 blocks.
// ---------------------------------------------------------------------------
__global__ __launch_bounds__(256) void mega_prep(
    const float* __restrict__ x, const float* __restrict__ W,
    const float* __restrict__ expert_A, const float* __restrict__ shared_A,
    const float* __restrict__ expert_B, const float* __restrict__ shared_B,
    const float* __restrict__ task_emb, const float* __restrict__ collab,
    __bf16* __restrict__ xb, __bf16* __restrict__ Wb,
    __bf16* __restrict__ caug, __bf16* __restrict__ pt, float* __restrict__ plog)
{
    const int bid = blockIdx.x;
    const int t = threadIdx.x;

    if (bid >= 512) {
        if (bid < 4608) {
            size_t idx = ((size_t)(bid - 512) * 256 + t) * 4;
            int o = (int)(idx >> 11), i = (int)(idx & 2047);
            float cw = 1.0f / (1.0f + expf(-collab[0]));
            float s = cw * 2.0f;
            float4 w = *(const float4*)&W[idx];
            float dx = 0.f, dy = 0.f, dz = 0.f, dw = 0.f;
            #pragma unroll
            for (int r = 0; r < 8; ++r) {
                float bs = shared_B[(size_t)o * RANK + r];
                float4 as = *(const float4*)&shared_A[(size_t)r * DIN + i];
                dx += bs * as.x; dy += bs * as.y; dz += bs * as.z; dw += bs * as.w;
            }
            bf16x4 h = { (__bf16)(w.x + s * dx), (__bf16)(w.y + s * dy),
                         (__bf16)(w.z + s * dz), (__bf16)(w.w + s * dw) };
            *(bf16x4*)&Wb[idx] = h;
        } else {
            int idx = ((bid - 4608) * 256 + t) * 4;   // over 2048*64
            int o = idx >> 6, k = idx & 63;           // k multiple of 4
            float cw = 1.0f / (1.0f + expf(-collab[0]));
            float s = (1.0f - cw) * 2.0f;
            float4 v = *(const float4*)&expert_B[((size_t)(k >> 3) * DOUT + o) * RANK + (k & 7)];
            bf16x4 h = { (__bf16)(s * v.x), (__bf16)(s * v.y),
                         (__bf16)(s * v.z), (__bf16)(s * v.w) };
            *(bf16x4*)&caug[idx] = h;
        }
        return;
    }

    // ---- gemm_t tile ----
    __shared__ __bf16 lsA[128 * 64];
    __shared__ __bf16 lsB[96 * 64];
    __shared__ float lsc[32];
    const int lane = t & 63;
    const int w = t >> 6;
    const int kc = bid & 7;
    const int m0 = (bid >> 3) * 128;

    f32x4 acc[2][5];
    #pragma unroll
    for (int a = 0; a < 2; ++a)
        #pragma unroll
        for (int c = 0; c < 5; ++c) acc[a][c] = (f32x4){0.f, 0.f, 0.f, 0.f};

    for (int it = 0; it < 4; ++it) {
        int k0 = kc * 256 + it * 64;
        #pragma unroll
        for (int q = 0; q < 4; ++q) {
            int row = q * 32 + (t >> 3), sl = t & 7, seg = sl ^ (row & 7);
            const float* gp = x + (size_t)(m0 + row) * DIN + k0 + seg * 8;
            float4 v0 = *(const float4*)gp;
            float4 v1 = *(const float4*)(gp + 4);
            bf16x8 h = { (__bf16)v0.x, (__bf16)v0.y, (__bf16)v0.z, (__bf16)v0.w,
                         (__bf16)v1.x, (__bf16)v1.y, (__bf16)v1.z, (__bf16)v1.w };
            *(bf16x8*)&lsA[row * 64 + sl * 8] = h;
            *(bf16x8*)&xb[(size_t)(m0 + row) * DIN + k0 + seg * 8] = h;
        }
        #pragma unroll
        for (int q = 0; q < 3; ++q) {
            int c = q * 256 + t;
            int row = c >> 3, sl = c & 7, seg = sl ^ (row & 7);
            bf16x8 h = { (__bf16)0.f, (__bf16)0.f, (__bf16)0.f, (__bf16)0.f,
                         (__bf16)0.f, (__bf16)0.f, (__bf16)0.f, (__bf16)0.f };
            if (row < 64) {
                const float* gp = expert_A + (size_t)row * DIN + k0 + seg * 8;
                float4 v0 = *(const float4*)gp, v1 = *(const float4*)(gp + 4);
                h = bf16x8{ (__bf16)v0.x, (__bf16)v0.y, (__bf16)v0.z, (__bf16)v0.w,
                            (__bf16)v1.x, (__bf16)v1.y, (__bf16)v1.z, (__bf16)v1.w };
            } else if (row < 72) {
                const float* gp = task_emb + (size_t)(row - 64) * DIN + k0 + seg * 8;
                float4 v0 = *(const float4*)gp, v1 = *(const float4*)(gp + 4);
                h = bf16x8{ (__bf16)v0.x, (__bf16)v0.y, (__bf16)v0.z, (__bf16)v0.w,
                            (__bf16)v1.x, (__bf16)v1.y, (__bf16)v1.z, (__bf16)v1.w };
            }
            *(bf16x8*)&lsB[row * 64 + sl * 8] = h;
        }
        __syncthreads();
        #pragma unroll
        for (int kk = 0; kk < 2; ++kk) {
            bf16x8 af[2], bfr[5];
            #pragma unroll
            for (int tm = 0; tm < 2; ++tm) {
                int r = w * 32 + tm * 16 + (lane & 15);
                int slot = (kk * 4 + (lane >> 4)) ^ (r & 7);
                af[tm] = *(const bf16x8*)&lsA[r * 64 + slot * 8];
            }
            #pragma unroll
            for (int tn = 0; tn < 5; ++tn) {
                int r = tn * 16 + (lane & 15);
                int slot = (kk * 4 + (lane >> 4)) ^ (r & 7);
                bfr[tn] = *(const bf16x8*)&lsB[r * 64 + slot * 8];
            }
            #pragma unroll
            for (int tm = 0; tm < 2; ++tm)
                #pragma unroll
                for (int tn = 0; tn < 5; ++tn)
                    acc[tm][tn] = __builtin_amdgcn_mfma_f32_16x16x32_bf16(
                        af[tm], bfr[tn], acc[tm][tn], 0, 0, 0);
        }
        __syncthreads();
    }

    #pragma unroll
    for (int tm = 0; tm < 2; ++tm)
        #pragma unroll
        for (int tn = 0; tn < 4; ++tn) {
            int col = tn * 16 + (lane & 15);
            #pragma unroll
            for (int v = 0; v < 4; ++v) {
                int row = m0 + w * 32 + tm * 16 + (lane >> 4) * 4 + v;
                pt[((size_t)kc * MTOT + row) * KE + col] = (__bf16)acc[tm][tn][v];
            }
        }

    float s = 0.f;
    #pragma unroll
    for (int tm = 0; tm < 2; ++tm)
        #pragma unroll
        for (int v = 0; v < 4; ++v) s += acc[tm][4][v];
    s += __shfl_down(s, 32);
    s += __shfl_down(s, 16);
    if (lane < 8) lsc[w * 8 + lane] = s;
    __syncthreads();
    if (t < 8)
        plog[bid * 8 + t] = lsc[t] + lsc[8 + t] + lsc[16 + t] + lsc[24 + t];
}

// ---------------------------------------------------------------------------
// K2 gemm_main: ROUND-7 SKELETON with the two NON-LOAD-BEARING barriers
// deleted (the ones between a wave's own ds_reads and its own MFMAs).
// Per K-tile now 2 regions, 2 barriers:
//   H0: {issue g2(kt+1); read B all + A fm0-3; MFMA fm0-3;
//        s_waitcnt vmcnt(8) lgkmcnt(0); BARRIER}   // publishes g2(kt)
//   H1: {issue g1(kt+2); read A fm4-7; MFMA fm4-7;
//        s_waitcnt vmcnt(8) lgkmcnt(0); BARRIER}   // publishes g1(kt+1)
// Effect: compiler interleaves later ds_reads under earlier MFMAs (fine
// lgkmcnt waits, m97-verified behavior) and waves de-skew within a region,
// so the LDS pipe and MFMA pipe overlap — the residual both R6 and R7
// shared (strict read/MFMA alternation) is removed.
// vmcnt ledger IDENTICAL to round 7 (same issue points, same waits, never
// 0 until tail: kt=31 H0 vmcnt(0); kt=30 H1 vmcnt(2)).
// lgkmcnt(0) in the trailing wait closes the rule-#18 hazard (compiler may
// sink register-only MFMAs past the barrier, leaving ds_reads in flight
// when the post-barrier DMA overwrites their LDS source); it is free since
// lgkm is naturally drained there by MFMA consumption.
// setprio removed from the main loop (proven only on lockstep structures;
// risks pinning the interleave this round exists to create).
// ---------------------------------------------------------------------------
#define ISSUE_G1(j) do {                                                      \
    const int nb_ = ((j) & 1) * 16384;                                        \
    const __bf16* a_ = gA + (j) * 64;                                         \
    const __bf16* b_ = gB + (j) * 64;                                         \
    __builtin_amdgcn_global_load_lds((GLOBAL_AS void*)(b_ + 0 * 64 * DIN),    \
        (LDS_AS void*)&lds[32768 + nb_ + 0 * 4096 + lbase], 16, 0, 0);        \
    __builtin_amdgcn_global_load_lds((GLOBAL_AS void*)(b_ + 1 * 64 * DIN),    \
        (LDS_AS void*)&lds[32768 + nb_ + 1 * 4096 + lbase], 16, 0, 0);        \
    __builtin_amdgcn_global_load_lds((GLOBAL_AS void*)(b_ + 2 * 64 * DIN),    \
        (LDS_AS void*)&lds[32768 + nb_ + 2 * 4096 + lbase], 16, 0, 0);        \
    __builtin_amdgcn_global_load_lds((GLOBAL_AS void*)(b_ + 3 * 64 * DIN),    \
        (LDS_AS void*)&lds[32768 + nb_ + 3 * 4096 + lbase], 16, 0, 0);        \
    __builtin_amdgcn_global_load_lds((GLOBAL_AS void*)(a_ + 0 * 64 * DIN),    \
        (LDS_AS void*)&lds[nb_ + 0 * 4096 + lbase], 16, 0, 0);                \
    __builtin_amdgcn_global_load_lds((GLOBAL_AS void*)(a_ + 2 * 64 * DIN),    \
        (LDS_AS void*)&lds[nb_ + 2 * 4096 + lbase], 16, 0, 0);                \
} while (0)

#define ISSUE_G2(j) do {                                                      \
    const int nb_ = ((j) & 1) * 16384;                                        \
    const __bf16* a_ = gA + (j) * 64;                                         \
    __builtin_amdgcn_global_load_lds((GLOBAL_AS void*)(a_ + 1 * 64 * DIN),    \
        (LDS_AS void*)&lds[nb_ + 1 * 4096 + lbase], 16, 0, 0);                \
    __builtin_amdgcn_global_load_lds((GLOBAL_AS void*)(a_ + 3 * 64 * DIN),    \
        (LDS_AS void*)&lds[nb_ + 3 * 4096 + lbase], 16, 0, 0);                \
} while (0)

__global__ __launch_bounds__(512, 2) void gemm_main(
    const __bf16* __restrict__ xb, const __bf16* __restrict__ Wb,
    const __bf16* __restrict__ pt, const __bf16* __restrict__ caug,
    const float* __restrict__ plog, const float* __restrict__ bias,
    float* __restrict__ out)
{
    __shared__ __bf16 lds[65536];   // 128 KiB: elements [A0|A1|B0|B1] 16K each
    const int t = threadIdx.x;
    const int lane = t & 63;
    const int wid = t >> 6;
    const int wm = wid >> 2, wn = wid & 3;      // 2x4 wave grid, 128x64 per wave
    const int bid = blockIdx.x;
    const int xcd = bid & 7, j = bid >> 3;
    const int m0 = (xcd * 4 + (j >> 3)) * 256;  // 4 m-tiles per XCD
    const int n0 = (j & 7) * 256;               // all 8 n-tiles per XCD
    const int b  = m0 >> 11;

    // staging addressing (pre-swizzled source -> linear LDS fill)
    const int srow = t >> 3;                    // 0..63
    const int sseg = (t & 7) ^ (srow & 7);
    const __bf16* gA = xb + (size_t)(m0 + srow) * DIN + sseg * 8;
    const __bf16* gB = Wb + (size_t)(n0 + srow) * DIN + sseg * 8;
    const int lbase = (t & ~63) * 8;            // wave-uniform LDS element base

    // fragment ds_read offsets (^32 flips slot bit2: other K-half)
    int aoff[8], boff[4];
    #pragma unroll
    for (int fm = 0; fm < 8; ++fm) {
        int r = wm * 128 + fm * 16 + (lane & 15);
        aoff[fm] = r * 64 + (((lane >> 4) ^ (r & 7)) * 8);
    }
    #pragma unroll
    for (int fn = 0; fn < 4; ++fn) {
        int r = wn * 64 + fn * 16 + (lane & 15);
        boff[fn] = r * 64 + (((lane >> 4) ^ (r & 7)) * 8);
    }

    f32x4 acc[8][4];
    #pragma unroll
    for (int i = 0; i < 8; ++i)
        #pragma unroll
        for (int jj = 0; jj < 4; ++jj) acc[i][jj] = (f32x4){0.f, 0.f, 0.f, 0.f};

    // prologue: g1(0)+g2(0)+g1(1) = 14 in flight; vmcnt(8) retires g1(0)
    ISSUE_G1(0); ISSUE_G2(0); ISSUE_G1(1);
    asm volatile("s_waitcnt vmcnt(8)" ::: "memory");
    BARRIER();

    // ---- main loop: K = 2048, 32 K-tiles of BK=64, 2 regions each ----
    for (int kt = 0; kt < 32; ++kt) {
        const int abase = (kt & 1) * 16384;
        const int bbase = 32768 + (kt & 1) * 16384;
        bf16x8 bfrag[4][2];
        bf16x8 afr[4][2];

        // -- H0: issue g2(kt+1); read B all + A fm0-3; MFMA fm0-3 --
        if (kt < 31) ISSUE_G2(kt + 1);
        #pragma unroll
        for (int fn = 0; fn < 4; ++fn) {
            bfrag[fn][0] = *(const bf16x8*)&lds[bbase + boff[fn]];
            bfrag[fn][1] = *(const bf16x8*)&lds[bbase + (boff[fn] ^ 32)];
        }
        #pragma unroll
        for (int i = 0; i < 4; ++i) {
            afr[i][0] = *(const bf16x8*)&lds[abase + aoff[i]];
            afr[i][1] = *(const bf16x8*)&lds[abase + (aoff[i] ^ 32)];
        }
        #pragma unroll
        for (int kk = 0; kk < 2; ++kk)
            #pragma unroll
            for (int i = 0; i < 4; ++i)
                #pragma unroll
                for (int fn = 0; fn < 4; ++fn)
                    acc[i][fn] = __builtin_amdgcn_mfma_f32_16x16x32_bf16(
                        afr[i][kk], bfrag[fn][kk], acc[i][fn], 0, 0, 0);
        if (kt < 31) asm volatile("s_waitcnt vmcnt(8) lgkmcnt(0)" ::: "memory");
        else         asm volatile("s_waitcnt vmcnt(0) lgkmcnt(0)" ::: "memory");
        BARRIER();                                  // publishes g2(kt) (A-odd)

        // -- H1: issue g1(kt+2); read A fm4-7; MFMA fm4-7 --
        if (kt < 30) ISSUE_G1(kt + 2);
        #pragma unroll
        for (int i = 0; i < 4; ++i) {
            afr[i][0] = *(const bf16x8*)&lds[abase + aoff[4 + i]];
            afr[i][1] = *(const bf16x8*)&lds[abase + (aoff[4 + i] ^ 32)];
        }
        #pragma unroll
        for (int kk = 0; kk < 2; ++kk)
            #pragma unroll
            for (int i = 0; i < 4; ++i)
                #pragma unroll
                for (int fn = 0; fn < 4; ++fn)
                    acc[4 + i][fn] = __builtin_amdgcn_mfma_f32_16x16x32_bf16(
                        afr[i][kk], bfrag[fn][kk], acc[4 + i][fn], 0, 0, 0);
        if (kt < 30)       asm volatile("s_waitcnt vmcnt(8) lgkmcnt(0)" ::: "memory");
        else if (kt == 30) asm volatile("s_waitcnt vmcnt(2) lgkmcnt(0)" ::: "memory");
        else               asm volatile("s_waitcnt lgkmcnt(0)" ::: "memory");
        BARRIER();                                  // publishes g1(kt+1)
    }

    // ---- correction phase (LDS buffers now free; vmcnt==0 here) ----
    // (a) caug -> B0 region (DMA, drained before (d))
    {
        const __bf16* gC = caug + (size_t)(n0 + srow) * KE + sseg * 8;
        #pragma unroll
        for (int q = 0; q < 4; ++q)
            __builtin_amdgcn_global_load_lds((GLOBAL_AS void*)(gC + q * 64 * KE),
                (LDS_AS void*)&lds[32768 + q * 4096 + lbase], 16, 0, 0);
    }
    // (b) logits: sum plog[b*128 .. +128][8] -> softmax factors f[8]
    float* scr = (float*)&lds[16384];           // overlay on A1 (512 + 8 f32)
    float* lgs = scr + 512;
    {
        const float* pb = plog + (size_t)b * 128 * 8;
        int e = t & 7, rr = t >> 3;             // rr 0..63
        scr[rr * 8 + e] = pb[rr * 8 + e] + pb[(rr + 64) * 8 + e];
    }
    asm volatile("s_waitcnt lgkmcnt(0)" ::: "memory");
    BARRIER();
    if (t < 8) {
        float s = 0.f;
        #pragma unroll
        for (int i = 0; i < 64; ++i) s += scr[i * 8 + t];
        lgs[t] = s;
    }
    asm volatile("s_waitcnt lgkmcnt(0)" ::: "memory");
    BARRIER();
    float f[NEXP];
    {
        float li[NEXP];
        #pragma unroll
        for (int e = 0; e < NEXP; ++e) li[e] = lgs[e] * (1.0f / (float)SEQ);
        float mx = li[0];
        #pragma unroll
        for (int e = 1; e < NEXP; ++e) mx = fmaxf(mx, li[e]);
        float den = 0.f;
        #pragma unroll
        for (int e = 0; e < NEXP; ++e) { f[e] = expf(li[e] - mx); den += f[e]; }
        float rden = 1.0f / den;
        #pragma unroll
        for (int e = 0; e < NEXP; ++e) f[e] *= rden;
    }
    // (c) build scaled tb tile into A0 (swizzled layout the readers expect)
    #pragma unroll
    for (int q = 0; q < 4; ++q) {
        int row = q * 64 + srow;
        const __bf16* p0 = pt + (size_t)(m0 + row) * KE + sseg * 8;
        float sum[8] = {0.f, 0.f, 0.f, 0.f, 0.f, 0.f, 0.f, 0.f};
        #pragma unroll
        for (int kc = 0; kc < NKC; ++kc) {
            bf16x8 v = *(const bf16x8*)(p0 + (size_t)kc * MTOT * KE);
            #pragma unroll
            for (int jj = 0; jj < 8; ++jj) sum[jj] += (float)v[jj];
        }
        float fe = f[sseg];                     // chunk spans exactly one expert
        bf16x8 h;
        #pragma unroll
        for (int jj = 0; jj < 8; ++jj) h[jj] = (__bf16)(sum[jj] * fe);
        *(bf16x8*)&lds[row * 64 + (t & 7) * 8] = h;
    }
    asm volatile("s_waitcnt vmcnt(0) lgkmcnt(0)" ::: "memory");
    BARRIER();
    // (d) correction MFMAs (K=64)
    {
        bf16x8 bfrag[4][2];
        #pragma unroll
        for (int fn = 0; fn < 4; ++fn) {
            bfrag[fn][0] = *(const bf16x8*)&lds[32768 + boff[fn]];
            bfrag[fn][1] = *(const bf16x8*)&lds[32768 + (boff[fn] ^ 32)];
        }
        #pragma unroll
        for (int fm = 0; fm < 8; ++fm) {
            bf16x8 a0 = *(const bf16x8*)&lds[aoff[fm]];
            bf16x8 a1 = *(const bf16x8*)&lds[aoff[fm] ^ 32];
            #pragma unroll
            for (int fn = 0; fn < 4; ++fn) {
                acc[fm][fn] = __builtin_amdgcn_mfma_f32_16x16x32_bf16(
                    a0, bfrag[fn][0], acc[fm][fn], 0, 0, 0);
                acc[fm][fn] = __builtin_amdgcn_mfma_f32_16x16x32_bf16(
                    a1, bfrag[fn][1], acc[fm][fn], 0, 0, 0);
            }
        }
    }

    // ---- epilogue: bias + fp32 store ----
    #pragma unroll
    for (int fn = 0; fn < 4; ++fn) {
        int col = n0 + wn * 64 + fn * 16 + (lane & 15);
        float bv = bias[col];
        #pragma unroll
        for (int fm = 0; fm < 8; ++fm) {
            int row = m0 + wm * 128 + fm * 16 + (lane >> 4) * 4;
            #pragma unroll
            for (int v = 0; v < 4; ++v)
                out[(size_t)(row + v) * DOUT + col] = acc[fm][fn][v] + bv;
        }
    }
}

// ---------------------------------------------------------------------------
// Workspace (bytes):
//   xb   @ 0         : 33,554,432   (8192x2048 bf16)
//   Wb   @ 33554432  :  8,388,608   (2048x2048 bf16, shared LoRA folded)
//   pt   @ 41943040  :  8,388,608   (8x8192x64 bf16)
//   caug @ 50331648  :    262,144   (2048x64 bf16)
//   plog @ 50593792  :     16,384   (512x8 f32, fully overwritten)
// ---------------------------------------------------------------------------
extern "C" void kernel_launch(void* const* d_in, const int* in_sizes, int n_in,
                              void* d_out, int out_size, void* d_ws, size_t ws_size,
                              hipStream_t stream)
{
    const float* x        = (const float*)d_in[0];
    const float* base_W   = (const float*)d_in[1];
    const float* base_b   = (const float*)d_in[2];
    const float* shared_A = (const float*)d_in[3];
    const float* shared_B = (const float*)d_in[4];
    const float* expert_A = (const float*)d_in[5];
    const float* expert_B = (const float*)d_in[6];
    const float* task_emb = (const float*)d_in[7];
    const float* collab_w = (const float*)d_in[8];
    float* out = (float*)d_out;

    char* ws = (char*)d_ws;
    __bf16* xb   = (__bf16*)(ws + 0);
    __bf16* Wb   = (__bf16*)(ws + 33554432);
    __bf16* pt   = (__bf16*)(ws + 41943040);
    __bf16* caug = (__bf16*)(ws + 50331648);
    float*  plog = (float*) (ws + 50593792);

    mega_prep<<<dim3(4736), 256, 0, stream>>>(x, base_W, expert_A, shared_A,
                                              expert_B, shared_B, task_emb, collab_w,
                                              xb, Wb, caug, pt, plog);
    gemm_main<<<dim3(256), 512, 0, stream>>>(xb, Wb, pt, caug, plog, base_b, out);
}

// Round 9
// 227.814 us; speedup vs baseline: 1.0432x; 1.0041x over previous
//
#include <hip/hip_runtime.h>
#include <hip/hip_bf16.h>
#include <math.h>

// COLoRALinear: B=4, S=2048, D_IN=D_OUT=2048, E=8, R=8, SCALING=2.0
#define BATCH 4
#define SEQ   2048
#define DIN   2048
#define DOUT  2048
#define NEXP  8
#define RANK  8
#define MTOT  (BATCH * SEQ)   // 8192
#define KE    64              // expert aug rank (shared LoRA folded into Wb)
#define NKC   8               // split-K chunks in gemm_t

typedef __bf16 bf16x8 __attribute__((ext_vector_type(8)));
typedef __bf16 bf16x4 __attribute__((ext_vector_type(4)));
typedef float  f32x4  __attribute__((ext_vector_type(4)));

#define GLOBAL_AS __attribute__((address_space(1)))
#define LDS_AS    __attribute__((address_space(3)))

// Barrier fused with a compiler memory fence (no op can slip between them).
#define BARRIER() asm volatile("s_barrier" ::: "memory")

// ---------------------------------------------------------------------------
// K1 mega_prep (unchanged, passed rounds 0/2/5/6/7/8): 4736 blocks.
// ---------------------------------------------------------------------------
__global__ __launch_bounds__(256) void mega_prep(
    const float* __restrict__ x, const float* __restrict__ W,
    const float* __restrict__ expert_A, const float* __restrict__ shared_A,
    const float* __restrict__ expert_B, const float* __restrict__ shared_B,
    const float* __restrict__ task_emb, const float* __restrict__ collab,
    __bf16* __restrict__ xb, __bf16* __restrict__ Wb,
    __bf16* __restrict__ caug, __bf16* __restrict__ pt, float* __restrict__ plog)
{
    const int bid = blockIdx.x;
    const int t = threadIdx.x;

    if (bid >= 512) {
        if (bid < 4608) {
            size_t idx = ((size_t)(bid - 512) * 256 + t) * 4;
            int o = (int)(idx >> 11), i = (int)(idx & 2047);
            float cw = 1.0f / (1.0f + expf(-collab[0]));
            float s = cw * 2.0f;
            float4 w = *(const float4*)&W[idx];
            float dx = 0.f, dy = 0.f, dz = 0.f, dw = 0.f;
            #pragma unroll
            for (int r = 0; r < 8; ++r) {
                float bs = shared_B[(size_t)o * RANK + r];
                float4 as = *(const float4*)&shared_A[(size_t)r * DIN + i];
                dx += bs * as.x; dy += bs * as.y; dz += bs * as.z; dw += bs * as.w;
            }
            bf16x4 h = { (__bf16)(w.x + s * dx), (__bf16)(w.y + s * dy),
                         (__bf16)(w.z + s * dz), (__bf16)(w.w + s * dw) };
            *(bf16x4*)&Wb[idx] = h;
        } else {
            int idx = ((bid - 4608) * 256 + t) * 4;   // over 2048*64
            int o = idx >> 6, k = idx & 63;           // k multiple of 4
            float cw = 1.0f / (1.0f + expf(-collab[0]));
            float s = (1.0f - cw) * 2.0f;
            float4 v = *(const float4*)&expert_B[((size_t)(k >> 3) * DOUT + o) * RANK + (k & 7)];
            bf16x4 h = { (__bf16)(s * v.x), (__bf16)(s * v.y),
                         (__bf16)(s * v.z), (__bf16)(s * v.w) };
            *(bf16x4*)&caug[idx] = h;
        }
        return;
    }

    // ---- gemm_t tile ----
    __shared__ __bf16 lsA[128 * 64];
    __shared__ __bf16 lsB[96 * 64];
    __shared__ float lsc[32];
    const int lane = t & 63;
    const int w = t >> 6;
    const int kc = bid & 7;
    const int m0 = (bid >> 3) * 128;

    f32x4 acc[2][5];
    #pragma unroll
    for (int a = 0; a < 2; ++a)
        #pragma unroll
        for (int c = 0; c < 5; ++c) acc[a][c] = (f32x4){0.f, 0.f, 0.f, 0.f};

    for (int it = 0; it < 4; ++it) {
        int k0 = kc * 256 + it * 64;
        #pragma unroll
        for (int q = 0; q < 4; ++q) {
            int row = q * 32 + (t >> 3), sl = t & 7, seg = sl ^ (row & 7);
            const float* gp = x + (size_t)(m0 + row) * DIN + k0 + seg * 8;
            float4 v0 = *(const float4*)gp;
            float4 v1 = *(const float4*)(gp + 4);
            bf16x8 h = { (__bf16)v0.x, (__bf16)v0.y, (__bf16)v0.z, (__bf16)v0.w,
                         (__bf16)v1.x, (__bf16)v1.y, (__bf16)v1.z, (__bf16)v1.w };
            *(bf16x8*)&lsA[row * 64 + sl * 8] = h;
            *(bf16x8*)&xb[(size_t)(m0 + row) * DIN + k0 + seg * 8] = h;
        }
        #pragma unroll
        for (int q = 0; q < 3; ++q) {
            int c = q * 256 + t;
            int row = c >> 3, sl = c & 7, seg = sl ^ (row & 7);
            bf16x8 h = { (__bf16)0.f, (__bf16)0.f, (__bf16)0.f, (__bf16)0.f,
                         (__bf16)0.f, (__bf16)0.f, (__bf16)0.f, (__bf16)0.f };
            if (row < 64) {
                const float* gp = expert_A + (size_t)row * DIN + k0 + seg * 8;
                float4 v0 = *(const float4*)gp, v1 = *(const float4*)(gp + 4);
                h = bf16x8{ (__bf16)v0.x, (__bf16)v0.y, (__bf16)v0.z, (__bf16)v0.w,
                            (__bf16)v1.x, (__bf16)v1.y, (__bf16)v1.z, (__bf16)v1.w };
            } else if (row < 72) {
                const float* gp = task_emb + (size_t)(row - 64) * DIN + k0 + seg * 8;
                float4 v0 = *(const float4*)gp, v1 = *(const float4*)(gp + 4);
                h = bf16x8{ (__bf16)v0.x, (__bf16)v0.y, (__bf16)v0.z, (__bf16)v0.w,
                            (__bf16)v1.x, (__bf16)v1.y, (__bf16)v1.z, (__bf16)v1.w };
            }
            *(bf16x8*)&lsB[row * 64 + sl * 8] = h;
        }
        __syncthreads();
        #pragma unroll
        for (int kk = 0; kk < 2; ++kk) {
            bf16x8 af[2], bfr[5];
            #pragma unroll
            for (int tm = 0; tm < 2; ++tm) {
                int r = w * 32 + tm * 16 + (lane & 15);
                int slot = (kk * 4 + (lane >> 4)) ^ (r & 7);
                af[tm] = *(const bf16x8*)&lsA[r * 64 + slot * 8];
            }
            #pragma unroll
            for (int tn = 0; tn < 5; ++tn) {
                int r = tn * 16 + (lane & 15);
                int slot = (kk * 4 + (lane >> 4)) ^ (r & 7);
                bfr[tn] = *(const bf16x8*)&lsB[r * 64 + slot * 8];
            }
            #pragma unroll
            for (int tm = 0; tm < 2; ++tm)
                #pragma unroll
                for (int tn = 0; tn < 5; ++tn)
                    acc[tm][tn] = __builtin_amdgcn_mfma_f32_16x16x32_bf16(
                        af[tm], bfr[tn], acc[tm][tn], 0, 0, 0);
        }
        __syncthreads();
    }

    #pragma unroll
    for (int tm = 0; tm < 2; ++tm)
        #pragma unroll
        for (int tn = 0; tn < 4; ++tn) {
            int col = tn * 16 + (lane & 15);
            #pragma unroll
            for (int v = 0; v < 4; ++v) {
                int row = m0 + w * 32 + tm * 16 + (lane >> 4) * 4 + v;
                pt[((size_t)kc * MTOT + row) * KE + col] = (__bf16)acc[tm][tn][v];
            }
        }

    float s = 0.f;
    #pragma unroll
    for (int tm = 0; tm < 2; ++tm)
        #pragma unroll
        for (int v = 0; v < 4; ++v) s += acc[tm][4][v];
    s += __shfl_down(s, 32);
    s += __shfl_down(s, 16);
    if (lane < 8) lsc[w * 8 + lane] = s;
    __syncthreads();
    if (t < 8)
        plog[bid * 8 + t] = lsc[t] + lsc[8 + t] + lsc[16 + t] + lsc[24 + t];
}

// ---------------------------------------------------------------------------
// K2 gemm_main: ROUND-8 PASSING SKELETON + T5 setprio re-added (only change).
// Structure (unchanged from R8): 2 merged regions per K-tile,
//   H0: {issue g2(kt+1); read B all + A fm0-3; MFMA fm0-3;
//        s_waitcnt vmcnt(8) lgkmcnt(0); BARRIER}   // publishes g2(kt)
//   H1: {issue g1(kt+2); read A fm4-7; MFMA fm4-7;
//        s_waitcnt vmcnt(8) lgkmcnt(0); BARRIER}   // publishes g1(kt+1)
// T5: setprio(1)..setprio(0) around each MFMA cluster. The structure now
// satisfies T5's prerequisite (phase-split + counted vmcnt -> waves in
// diverse roles per region); m218b/m224 isolate +21-39% in this regime.
// Mechanism: CU scheduler favors the MFMA-burst wave over read/stage-issuing
// waves, compressing the MFMA stretch; LDS reads fill the gaps.
// vmcnt ledger IDENTICAL to R8 (same issue points, same waits, never 0
// until tail: kt=30 H1 vmcnt(2); kt=31 H0 vmcnt(0)).
// ---------------------------------------------------------------------------
#define ISSUE_G1(j) do {                                                      \
    const int nb_ = ((j) & 1) * 16384;                                        \
    const __bf16* a_ = gA + (j) * 64;                                         \
    const __bf16* b_ = gB + (j) * 64;                                         \
    __builtin_amdgcn_global_load_lds((GLOBAL_AS void*)(b_ + 0 * 64 * DIN),    \
        (LDS_AS void*)&lds[32768 + nb_ + 0 * 4096 + lbase], 16, 0, 0);        \
    __builtin_amdgcn_global_load_lds((GLOBAL_AS void*)(b_ + 1 * 64 * DIN),    \
        (LDS_AS void*)&lds[32768 + nb_ + 1 * 4096 + lbase], 16, 0, 0);        \
    __builtin_amdgcn_global_load_lds((GLOBAL_AS void*)(b_ + 2 * 64 * DIN),    \
        (LDS_AS void*)&lds[32768 + nb_ + 2 * 4096 + lbase], 16, 0, 0);        \
    __builtin_amdgcn_global_load_lds((GLOBAL_AS void*)(b_ + 3 * 64 * DIN),    \
        (LDS_AS void*)&lds[32768 + nb_ + 3 * 4096 + lbase], 16, 0, 0);        \
    __builtin_amdgcn_global_load_lds((GLOBAL_AS void*)(a_ + 0 * 64 * DIN),    \
        (LDS_AS void*)&lds[nb_ + 0 * 4096 + lbase], 16, 0, 0);                \
    __builtin_amdgcn_global_load_lds((GLOBAL_AS void*)(a_ + 2 * 64 * DIN),    \
        (LDS_AS void*)&lds[nb_ + 2 * 4096 + lbase], 16, 0, 0);                \
} while (0)

#define ISSUE_G2(j) do {                                                      \
    const int nb_ = ((j) & 1) * 16384;                                        \
    const __bf16* a_ = gA + (j) * 64;                                         \
    __builtin_amdgcn_global_load_lds((GLOBAL_AS void*)(a_ + 1 * 64 * DIN),    \
        (LDS_AS void*)&lds[nb_ + 1 * 4096 + lbase], 16, 0, 0);                \
    __builtin_amdgcn_global_load_lds((GLOBAL_AS void*)(a_ + 3 * 64 * DIN),    \
        (LDS_AS void*)&lds[nb_ + 3 * 4096 + lbase], 16, 0, 0);                \
} while (0)

__global__ __launch_bounds__(512, 2) void gemm_main(
    const __bf16* __restrict__ xb, const __bf16* __restrict__ Wb,
    const __bf16* __restrict__ pt, const __bf16* __restrict__ caug,
    const float* __restrict__ plog, const float* __restrict__ bias,
    float* __restrict__ out)
{
    __shared__ __bf16 lds[65536];   // 128 KiB: elements [A0|A1|B0|B1] 16K each
    const int t = threadIdx.x;
    const int lane = t & 63;
    const int wid = t >> 6;
    const int wm = wid >> 2, wn = wid & 3;      // 2x4 wave grid, 128x64 per wave
    const int bid = blockIdx.x;
    const int xcd = bid & 7, j = bid >> 3;
    const int m0 = (xcd * 4 + (j >> 3)) * 256;  // 4 m-tiles per XCD
    const int n0 = (j & 7) * 256;               // all 8 n-tiles per XCD
    const int b  = m0 >> 11;

    // staging addressing (pre-swizzled source -> linear LDS fill)
    const int srow = t >> 3;                    // 0..63
    const int sseg = (t & 7) ^ (srow & 7);
    const __bf16* gA = xb + (size_t)(m0 + srow) * DIN + sseg * 8;
    const __bf16* gB = Wb + (size_t)(n0 + srow) * DIN + sseg * 8;
    const int lbase = (t & ~63) * 8;            // wave-uniform LDS element base

    // fragment ds_read offsets (^32 flips slot bit2: other K-half)
    int aoff[8], boff[4];
    #pragma unroll
    for (int fm = 0; fm < 8; ++fm) {
        int r = wm * 128 + fm * 16 + (lane & 15);
        aoff[fm] = r * 64 + (((lane >> 4) ^ (r & 7)) * 8);
    }
    #pragma unroll
    for (int fn = 0; fn < 4; ++fn) {
        int r = wn * 64 + fn * 16 + (lane & 15);
        boff[fn] = r * 64 + (((lane >> 4) ^ (r & 7)) * 8);
    }

    f32x4 acc[8][4];
    #pragma unroll
    for (int i = 0; i < 8; ++i)
        #pragma unroll
        for (int jj = 0; jj < 4; ++jj) acc[i][jj] = (f32x4){0.f, 0.f, 0.f, 0.f};

    // prologue: g1(0)+g2(0)+g1(1) = 14 in flight; vmcnt(8) retires g1(0)
    ISSUE_G1(0); ISSUE_G2(0); ISSUE_G1(1);
    asm volatile("s_waitcnt vmcnt(8)" ::: "memory");
    BARRIER();

    // ---- main loop: K = 2048, 32 K-tiles of BK=64, 2 regions each ----
    for (int kt = 0; kt < 32; ++kt) {
        const int abase = (kt & 1) * 16384;
        const int bbase = 32768 + (kt & 1) * 16384;
        bf16x8 bfrag[4][2];
        bf16x8 afr[4][2];

        // -- H0: issue g2(kt+1); read B all + A fm0-3; MFMA fm0-3 --
        if (kt < 31) ISSUE_G2(kt + 1);
        #pragma unroll
        for (int fn = 0; fn < 4; ++fn) {
            bfrag[fn][0] = *(const bf16x8*)&lds[bbase + boff[fn]];
            bfrag[fn][1] = *(const bf16x8*)&lds[bbase + (boff[fn] ^ 32)];
        }
        #pragma unroll
        for (int i = 0; i < 4; ++i) {
            afr[i][0] = *(const bf16x8*)&lds[abase + aoff[i]];
            afr[i][1] = *(const bf16x8*)&lds[abase + (aoff[i] ^ 32)];
        }
        __builtin_amdgcn_s_setprio(1);
        #pragma unroll
        for (int kk = 0; kk < 2; ++kk)
            #pragma unroll
            for (int i = 0; i < 4; ++i)
                #pragma unroll
                for (int fn = 0; fn < 4; ++fn)
                    acc[i][fn] = __builtin_amdgcn_mfma_f32_16x16x32_bf16(
                        afr[i][kk], bfrag[fn][kk], acc[i][fn], 0, 0, 0);
        __builtin_amdgcn_s_setprio(0);
        if (kt < 31) asm volatile("s_waitcnt vmcnt(8) lgkmcnt(0)" ::: "memory");
        else         asm volatile("s_waitcnt vmcnt(0) lgkmcnt(0)" ::: "memory");
        BARRIER();                                  // publishes g2(kt) (A-odd)

        // -- H1: issue g1(kt+2); read A fm4-7; MFMA fm4-7 --
        if (kt < 30) ISSUE_G1(kt + 2);
        #pragma unroll
        for (int i = 0; i < 4; ++i) {
            afr[i][0] = *(const bf16x8*)&lds[abase + aoff[4 + i]];
            afr[i][1] = *(const bf16x8*)&lds[abase + (aoff[4 + i] ^ 32)];
        }
        __builtin_amdgcn_s_setprio(1);
        #pragma unroll
        for (int kk = 0; kk < 2; ++kk)
            #pragma unroll
            for (int i = 0; i < 4; ++i)
                #pragma unroll
                for (int fn = 0; fn < 4; ++fn)
                    acc[4 + i][fn] = __builtin_amdgcn_mfma_f32_16x16x32_bf16(
                        afr[i][kk], bfrag[fn][kk], acc[4 + i][fn], 0, 0, 0);
        __builtin_amdgcn_s_setprio(0);
        if (kt < 30)       asm volatile("s_waitcnt vmcnt(8) lgkmcnt(0)" ::: "memory");
        else if (kt == 30) asm volatile("s_waitcnt vmcnt(2) lgkmcnt(0)" ::: "memory");
        else               asm volatile("s_waitcnt lgkmcnt(0)" ::: "memory");
        BARRIER();                                  // publishes g1(kt+1)
    }

    // ---- correction phase (LDS buffers now free; vmcnt==0 here) ----
    // (a) caug -> B0 region (DMA, drained before (d))
    {
        const __bf16* gC = caug + (size_t)(n0 + srow) * KE + sseg * 8;
        #pragma unroll
        for (int q = 0; q < 4; ++q)
            __builtin_amdgcn_global_load_lds((GLOBAL_AS void*)(gC + q * 64 * KE),
                (LDS_AS void*)&lds[32768 + q * 4096 + lbase], 16, 0, 0);
    }
    // (b) logits: sum plog[b*128 .. +128][8] -> softmax factors f[8]
    float* scr = (float*)&lds[16384];           // overlay on A1 (512 + 8 f32)
    float* lgs = scr + 512;
    {
        const float* pb = plog + (size_t)b * 128 * 8;
        int e = t & 7, rr = t >> 3;             // rr 0..63
        scr[rr * 8 + e] = pb[rr * 8 + e] + pb[(rr + 64) * 8 + e];
    }
    asm volatile("s_waitcnt lgkmcnt(0)" ::: "memory");
    BARRIER();
    if (t < 8) {
        float s = 0.f;
        #pragma unroll
        for (int i = 0; i < 64; ++i) s += scr[i * 8 + t];
        lgs[t] = s;
    }
    asm volatile("s_waitcnt lgkmcnt(0)" ::: "memory");
    BARRIER();
    float f[NEXP];
    {
        float li[NEXP];
        #pragma unroll
        for (int e = 0; e < NEXP; ++e) li[e] = lgs[e] * (1.0f / (float)SEQ);
        float mx = li[0];
        #pragma unroll
        for (int e = 1; e < NEXP; ++e) mx = fmaxf(mx, li[e]);
        float den = 0.f;
        #pragma unroll
        for (int e = 0; e < NEXP; ++e) { f[e] = expf(li[e] - mx); den += f[e]; }
        float rden = 1.0f / den;
        #pragma unroll
        for (int e = 0; e < NEXP; ++e) f[e] *= rden;
    }
    // (c) build scaled tb tile into A0 (swizzled layout the readers expect)
    #pragma unroll
    for (int q = 0; q < 4; ++q) {
        int row = q * 64 + srow;
        const __bf16* p0 = pt + (size_t)(m0 + row) * KE + sseg * 8;
        float sum[8] = {0.f, 0.f, 0.f, 0.f, 0.f, 0.f, 0.f, 0.f};
        #pragma unroll
        for (int kc = 0; kc < NKC; ++kc) {
            bf16x8 v = *(const bf16x8*)(p0 + (size_t)kc * MTOT * KE);
            #pragma unroll
            for (int jj = 0; jj < 8; ++jj) sum[jj] += (float)v[jj];
        }
        float fe = f[sseg];                     // chunk spans exactly one expert
        bf16x8 h;
        #pragma unroll
        for (int jj = 0; jj < 8; ++jj) h[jj] = (__bf16)(sum[jj] * fe);
        *(bf16x8*)&lds[row * 64 + (t & 7) * 8] = h;
    }
    asm volatile("s_waitcnt vmcnt(0) lgkmcnt(0)" ::: "memory");
    BARRIER();
    // (d) correction MFMAs (K=64)
    {
        bf16x8 bfrag[4][2];
        #pragma unroll
        for (int fn = 0; fn < 4; ++fn) {
            bfrag[fn][0] = *(const bf16x8*)&lds[32768 + boff[fn]];
            bfrag[fn][1] = *(const bf16x8*)&lds[32768 + (boff[fn] ^ 32)];
        }
        #pragma unroll
        for (int fm = 0; fm < 8; ++fm) {
            bf16x8 a0 = *(const bf16x8*)&lds[aoff[fm]];
            bf16x8 a1 = *(const bf16x8*)&lds[aoff[fm] ^ 32];
            #pragma unroll
            for (int fn = 0; fn < 4; ++fn) {
                acc[fm][fn] = __builtin_amdgcn_mfma_f32_16x16x32_bf16(
                    a0, bfrag[fn][0], acc[fm][fn], 0, 0, 0);
                acc[fm][fn] = __builtin_amdgcn_mfma_f32_16x16x32_bf16(
                    a1, bfrag[fn][1], acc[fm][fn], 0, 0, 0);
            }
        }
    }

    // ---- epilogue: bias + fp32 store ----
    #pragma unroll
    for (int fn = 0; fn < 4; ++fn) {
        int col = n0 + wn * 64 + fn * 16 + (lane & 15);
        float bv = bias[col];
        #pragma unroll
        for (int fm = 0; fm < 8; ++fm) {
            int row = m0 + wm * 128 + fm * 16 + (lane >> 4) * 4;
            #pragma unroll
            for (int v = 0; v < 4; ++v)
                out[(size_t)(row + v) * DOUT + col] = acc[fm][fn][v] + bv;
        }
    }
}

// ---------------------------------------------------------------------------
// Workspace (bytes):
//   xb   @ 0         : 33,554,432   (8192x2048 bf16)
//   Wb   @ 33554432  :  8,388,608   (2048x2048 bf16, shared LoRA folded)
//   pt   @ 41943040  :  8,388,608   (8x8192x64 bf16)
//   caug @ 50331648  :    262,144   (2048x64 bf16)
//   plog @ 50593792  :     16,384   (512x8 f32, fully overwritten)
// ---------------------------------------------------------------------------
extern "C" void kernel_launch(void* const* d_in, const int* in_sizes, int n_in,
                              void* d_out, int out_size, void* d_ws, size_t ws_size,
                              hipStream_t stream)
{
    const float* x        = (const float*)d_in[0];
    const float* base_W   = (const float*)d_in[1];
    const float* base_b   = (const float*)d_in[2];
    const float* shared_A = (const float*)d_in[3];
    const float* shared_B = (const float*)d_in[4];
    const float* expert_A = (const float*)d_in[5];
    const float* expert_B = (const float*)d_in[6];
    const float* task_emb = (const float*)d_in[7];
    const float* collab_w = (const float*)d_in[8];
    float* out = (float*)d_out;

    char* ws = (char*)d_ws;
    __bf16* xb   = (__bf16*)(ws + 0);
    __bf16* Wb   = (__bf16*)(ws + 33554432);
    __bf16* pt   = (__bf16*)(ws + 41943040);
    __bf16* caug = (__bf16*)(ws + 50331648);
    float*  plog = (float*) (ws + 50593792);

    mega_prep<<<dim3(4736), 256, 0, stream>>>(x, base_W, expert_A, shared_A,
                                              expert_B, shared_B, task_emb, collab_w,
                                              xb, Wb, caug, pt, plog);
    gemm_main<<<dim3(256), 512, 0, stream>>>(xb, Wb, pt, caug, plog, base_b, out);
}

// Round 10
// 226.410 us; speedup vs baseline: 1.0497x; 1.0062x over previous
//
#include <hip/hip_runtime.h>
#include <hip/hip_bf16.h>
#include <math.h>

// COLoRALinear: B=4, S=2048, D_IN=D_OUT=2048, E=8, R=8, SCALING=2.0
#define BATCH 4
#define SEQ   2048
#define DIN   2048
#define DOUT  2048
#define NEXP  8
#define RANK  8
#define MTOT  (BATCH * SEQ)   // 8192
#define KE    64              // expert aug rank (shared LoRA folded into Wb)
#define NKC   8               // split-K chunks in gemm_t

typedef __bf16 bf16x8 __attribute__((ext_vector_type(8)));
typedef __bf16 bf16x4 __attribute__((ext_vector_type(4)));
typedef float  f32x4  __attribute__((ext_vector_type(4)));

#define GLOBAL_AS __attribute__((address_space(1)))
#define LDS_AS    __attribute__((address_space(3)))

// Barrier fused with a compiler memory fence (no op can slip between them).
#define BARRIER() asm volatile("s_barrier" ::: "memory")

#define CVT8(v0, v1) bf16x8{ (__bf16)(v0).x, (__bf16)(v0).y, (__bf16)(v0).z, (__bf16)(v0).w, \
                             (__bf16)(v1).x, (__bf16)(v1).y, (__bf16)(v1).z, (__bf16)(v1).w }

// ---------------------------------------------------------------------------
// K1 mega_prep: 4736 blocks. Wb/caug sections unchanged (streaming, fine).
// gemm_t section REWRITTEN this round: register-prefetch pipeline.
//   Old: 4x { load -> LDS -> __syncthreads (vmcnt(0) drain) -> MFMA -> sync }
//        -> every iteration exposes full HBM latency (the R2-era antipattern).
//   New: loads for it+1 issued into regs AFTER the LDS-write of it, BEFORE
//        the compute barrier; barriers are fused lgkmcnt(0)+s_barrier (no
//        vmcnt drain) -> x/B loads fly during the MFMA region; consumption
//        waits via register deps only. LDS layout/swizzle/compute unchanged.
//   lgkmcnt(0) before EACH barrier: publishes ds_writes (barrier 1) and
//   completes ds_reads before next overwrite (barrier 2, rule-#18 hazard).
// ---------------------------------------------------------------------------
__global__ __launch_bounds__(256) void mega_prep(
    const float* __restrict__ x, const float* __restrict__ W,
    const float* __restrict__ expert_A, const float* __restrict__ shared_A,
    const float* __restrict__ expert_B, const float* __restrict__ shared_B,
    const float* __restrict__ task_emb, const float* __restrict__ collab,
    __bf16* __restrict__ xb, __bf16* __restrict__ Wb,
    __bf16* __restrict__ caug, __bf16* __restrict__ pt, float* __restrict__ plog)
{
    const int bid = blockIdx.x;
    const int t = threadIdx.x;

    if (bid >= 512) {
        if (bid < 4608) {
            size_t idx = ((size_t)(bid - 512) * 256 + t) * 4;
            int o = (int)(idx >> 11), i = (int)(idx & 2047);
            float cw = 1.0f / (1.0f + expf(-collab[0]));
            float s = cw * 2.0f;
            float4 w = *(const float4*)&W[idx];
            float dx = 0.f, dy = 0.f, dz = 0.f, dw = 0.f;
            #pragma unroll
            for (int r = 0; r < 8; ++r) {
                float bs = shared_B[(size_t)o * RANK + r];
                float4 as = *(const float4*)&shared_A[(size_t)r * DIN + i];
                dx += bs * as.x; dy += bs * as.y; dz += bs * as.z; dw += bs * as.w;
            }
            bf16x4 h = { (__bf16)(w.x + s * dx), (__bf16)(w.y + s * dy),
                         (__bf16)(w.z + s * dz), (__bf16)(w.w + s * dw) };
            *(bf16x4*)&Wb[idx] = h;
        } else {
            int idx = ((bid - 4608) * 256 + t) * 4;   // over 2048*64
            int o = idx >> 6, k = idx & 63;           // k multiple of 4
            float cw = 1.0f / (1.0f + expf(-collab[0]));
            float s = (1.0f - cw) * 2.0f;
            float4 v = *(const float4*)&expert_B[((size_t)(k >> 3) * DOUT + o) * RANK + (k & 7)];
            bf16x4 h = { (__bf16)(s * v.x), (__bf16)(s * v.y),
                         (__bf16)(s * v.z), (__bf16)(s * v.w) };
            *(bf16x4*)&caug[idx] = h;
        }
        return;
    }

    // ---- gemm_t tile (pipelined) ----
    __shared__ __bf16 lsA[128 * 64];
    __shared__ __bf16 lsB[96 * 64];
    __shared__ float lsc[32];
    const int lane = t & 63;
    const int w = t >> 6;
    const int kc = bid & 7;
    const int m0 = (bid >> 3) * 128;
    // staging geometry: row_q = q*32 + r5; seg is q- and it-invariant
    // (q*32 and it*64 are 0 mod 8, so row&7 == r5&7 always).
    const int r5 = t >> 3, sl = t & 7, seg = sl ^ (r5 & 7);

    f32x4 acc[2][5];
    #pragma unroll
    for (int a = 0; a < 2; ++a)
        #pragma unroll
        for (int c = 0; c < 5; ++c) acc[a][c] = (f32x4){0.f, 0.f, 0.f, 0.f};

    const float* xp0 = x + (size_t)(m0 +      r5) * DIN + kc * 256 + seg * 8;
    const float* xp1 = x + (size_t)(m0 + 32 + r5) * DIN + kc * 256 + seg * 8;
    const float* xp2 = x + (size_t)(m0 + 64 + r5) * DIN + kc * 256 + seg * 8;
    const float* xp3 = x + (size_t)(m0 + 96 + r5) * DIN + kc * 256 + seg * 8;
    const float* bq0 = expert_A + (size_t)r5        * DIN + kc * 256 + seg * 8;
    const float* bq1 = expert_A + (size_t)(32 + r5) * DIN + kc * 256 + seg * 8;
    const float* bq2 = task_emb + (size_t)r5        * DIN + kc * 256 + seg * 8;

    float4 xv[4][2], bv[3][2];

#define MP_LOAD(ofs) do {                                                              \
    xv[0][0] = *(const float4*)(xp0 + (ofs)); xv[0][1] = *(const float4*)(xp0 + (ofs) + 4); \
    xv[1][0] = *(const float4*)(xp1 + (ofs)); xv[1][1] = *(const float4*)(xp1 + (ofs) + 4); \
    xv[2][0] = *(const float4*)(xp2 + (ofs)); xv[2][1] = *(const float4*)(xp2 + (ofs) + 4); \
    xv[3][0] = *(const float4*)(xp3 + (ofs)); xv[3][1] = *(const float4*)(xp3 + (ofs) + 4); \
    bv[0][0] = *(const float4*)(bq0 + (ofs)); bv[0][1] = *(const float4*)(bq0 + (ofs) + 4); \
    bv[1][0] = *(const float4*)(bq1 + (ofs)); bv[1][1] = *(const float4*)(bq1 + (ofs) + 4); \
    if (t < 64) {                                                                      \
        bv[2][0] = *(const float4*)(bq2 + (ofs)); bv[2][1] = *(const float4*)(bq2 + (ofs) + 4); \
    }                                                                                  \
} while (0)

    MP_LOAD(0);
    for (int it = 0; it < 4; ++it) {
        const int k0 = kc * 256 + it * 64;
        // ---- write stage (consumes xv/bv; reg-dep waits only) ----
        {
            bf16x8 h;
            h = CVT8(xv[0][0], xv[0][1]);
            *(bf16x8*)&lsA[(r5)      * 64 + sl * 8] = h;
            *(bf16x8*)&xb[(size_t)(m0 +      r5) * DIN + k0 + seg * 8] = h;
            h = CVT8(xv[1][0], xv[1][1]);
            *(bf16x8*)&lsA[(32 + r5) * 64 + sl * 8] = h;
            *(bf16x8*)&xb[(size_t)(m0 + 32 + r5) * DIN + k0 + seg * 8] = h;
            h = CVT8(xv[2][0], xv[2][1]);
            *(bf16x8*)&lsA[(64 + r5) * 64 + sl * 8] = h;
            *(bf16x8*)&xb[(size_t)(m0 + 64 + r5) * DIN + k0 + seg * 8] = h;
            h = CVT8(xv[3][0], xv[3][1]);
            *(bf16x8*)&lsA[(96 + r5) * 64 + sl * 8] = h;
            *(bf16x8*)&xb[(size_t)(m0 + 96 + r5) * DIN + k0 + seg * 8] = h;
            h = CVT8(bv[0][0], bv[0][1]);
            *(bf16x8*)&lsB[(r5)      * 64 + sl * 8] = h;
            h = CVT8(bv[1][0], bv[1][1]);
            *(bf16x8*)&lsB[(32 + r5) * 64 + sl * 8] = h;
            bf16x8 h2 = { (__bf16)0.f, (__bf16)0.f, (__bf16)0.f, (__bf16)0.f,
                          (__bf16)0.f, (__bf16)0.f, (__bf16)0.f, (__bf16)0.f };
            if (t < 64) h2 = CVT8(bv[2][0], bv[2][1]);
            *(bf16x8*)&lsB[(64 + r5) * 64 + sl * 8] = h2;
        }
        // ---- prefetch next iteration (flies through the MFMA region) ----
        if (it < 3) MP_LOAD((it + 1) * 64);
        asm volatile("s_waitcnt lgkmcnt(0)" ::: "memory");  // publish ds_writes
        BARRIER();
        // ---- compute (unchanged) ----
        #pragma unroll
        for (int kk = 0; kk < 2; ++kk) {
            bf16x8 af[2], bfr[5];
            #pragma unroll
            for (int tm = 0; tm < 2; ++tm) {
                int r = w * 32 + tm * 16 + (lane & 15);
                int slot = (kk * 4 + (lane >> 4)) ^ (r & 7);
                af[tm] = *(const bf16x8*)&lsA[r * 64 + slot * 8];
            }
            #pragma unroll
            for (int tn = 0; tn < 5; ++tn) {
                int r = tn * 16 + (lane & 15);
                int slot = (kk * 4 + (lane >> 4)) ^ (r & 7);
                bfr[tn] = *(const bf16x8*)&lsB[r * 64 + slot * 8];
            }
            #pragma unroll
            for (int tm = 0; tm < 2; ++tm)
                #pragma unroll
                for (int tn = 0; tn < 5; ++tn)
                    acc[tm][tn] = __builtin_amdgcn_mfma_f32_16x16x32_bf16(
                        af[tm], bfr[tn], acc[tm][tn], 0, 0, 0);
        }
        asm volatile("s_waitcnt lgkmcnt(0)" ::: "memory");  // reads done (WAR)
        BARRIER();
    }

    // pt stores (cols 0-63)
    #pragma unroll
    for (int tm = 0; tm < 2; ++tm)
        #pragma unroll
        for (int tn = 0; tn < 4; ++tn) {
            int col = tn * 16 + (lane & 15);
            #pragma unroll
            for (int v = 0; v < 4; ++v) {
                int row = m0 + w * 32 + tm * 16 + (lane >> 4) * 4 + v;
                pt[((size_t)kc * MTOT + row) * KE + col] = (__bf16)acc[tm][tn][v];
            }
        }

    // partial logits (cols 64-71 live in frag tn=4, lanes with (lane&15)<8)
    float s = 0.f;
    #pragma unroll
    for (int tm = 0; tm < 2; ++tm)
        #pragma unroll
        for (int v = 0; v < 4; ++v) s += acc[tm][4][v];
    s += __shfl_down(s, 32);
    s += __shfl_down(s, 16);
    if (lane < 8) lsc[w * 8 + lane] = s;
    __syncthreads();
    if (t < 8)
        plog[bid * 8 + t] = lsc[t] + lsc[8 + t] + lsc[16 + t] + lsc[24 + t];
}

// ---------------------------------------------------------------------------
// K2 gemm_main: EXACT ROUND-8 PASSING KERNEL (setprio reverted — R9 A/B
// showed T5 is null-to-negative on the merged-region structure, m190-class).
// 2 merged regions per K-tile:
//   H0: {issue g2(kt+1); read B all + A fm0-3; MFMA fm0-3;
//        s_waitcnt vmcnt(8) lgkmcnt(0); BARRIER}   // publishes g2(kt)
//   H1: {issue g1(kt+2); read A fm4-7; MFMA fm4-7;
//        s_waitcnt vmcnt(8) lgkmcnt(0); BARRIER}   // publishes g1(kt+1)
// vmcnt never 0 until tail: kt=30 H1 vmcnt(2); kt=31 H0 vmcnt(0).
// ---------------------------------------------------------------------------
#define ISSUE_G1(j) do {                                                      \
    const int nb_ = ((j) & 1) * 16384;                                        \
    const __bf16* a_ = gA + (j) * 64;                                         \
    const __bf16* b_ = gB + (j) * 64;                                         \
    __builtin_amdgcn_global_load_lds((GLOBAL_AS void*)(b_ + 0 * 64 * DIN),    \
        (LDS_AS void*)&lds[32768 + nb_ + 0 * 4096 + lbase], 16, 0, 0);        \
    __builtin_amdgcn_global_load_lds((GLOBAL_AS void*)(b_ + 1 * 64 * DIN),    \
        (LDS_AS void*)&lds[32768 + nb_ + 1 * 4096 + lbase], 16, 0, 0);        \
    __builtin_amdgcn_global_load_lds((GLOBAL_AS void*)(b_ + 2 * 64 * DIN),    \
        (LDS_AS void*)&lds[32768 + nb_ + 2 * 4096 + lbase], 16, 0, 0);        \
    __builtin_amdgcn_global_load_lds((GLOBAL_AS void*)(b_ + 3 * 64 * DIN),    \
        (LDS_AS void*)&lds[32768 + nb_ + 3 * 4096 + lbase], 16, 0, 0);        \
    __builtin_amdgcn_global_load_lds((GLOBAL_AS void*)(a_ + 0 * 64 * DIN),    \
        (LDS_AS void*)&lds[nb_ + 0 * 4096 + lbase], 16, 0, 0);                \
    __builtin_amdgcn_global_load_lds((GLOBAL_AS void*)(a_ + 2 * 64 * DIN),    \
        (LDS_AS void*)&lds[nb_ + 2 * 4096 + lbase], 16, 0, 0);                \
} while (0)

#define ISSUE_G2(j) do {                                                      \
    const int nb_ = ((j) & 1) * 16384;                                        \
    const __bf16* a_ = gA + (j) * 64;                                         \
    __builtin_amdgcn_global_load_lds((GLOBAL_AS void*)(a_ + 1 * 64 * DIN),    \
        (LDS_AS void*)&lds[nb_ + 1 * 4096 + lbase], 16, 0, 0);                \
    __builtin_amdgcn_global_load_lds((GLOBAL_AS void*)(a_ + 3 * 64 * DIN),    \
        (LDS_AS void*)&lds[nb_ + 3 * 4096 + lbase], 16, 0, 0);                \
} while (0)

__global__ __launch_bounds__(512, 2) void gemm_main(
    const __bf16* __restrict__ xb, const __bf16* __restrict__ Wb,
    const __bf16* __restrict__ pt, const __bf16* __restrict__ caug,
    const float* __restrict__ plog, const float* __restrict__ bias,
    float* __restrict__ out)
{
    __shared__ __bf16 lds[65536];   // 128 KiB: elements [A0|A1|B0|B1] 16K each
    const int t = threadIdx.x;
    const int lane = t & 63;
    const int wid = t >> 6;
    const int wm = wid >> 2, wn = wid & 3;      // 2x4 wave grid, 128x64 per wave
    const int bid = blockIdx.x;
    const int xcd = bid & 7, j = bid >> 3;
    const int m0 = (xcd * 4 + (j >> 3)) * 256;  // 4 m-tiles per XCD
    const int n0 = (j & 7) * 256;               // all 8 n-tiles per XCD
    const int b  = m0 >> 11;

    // staging addressing (pre-swizzled source -> linear LDS fill)
    const int srow = t >> 3;                    // 0..63
    const int sseg = (t & 7) ^ (srow & 7);
    const __bf16* gA = xb + (size_t)(m0 + srow) * DIN + sseg * 8;
    const __bf16* gB = Wb + (size_t)(n0 + srow) * DIN + sseg * 8;
    const int lbase = (t & ~63) * 8;            // wave-uniform LDS element base

    // fragment ds_read offsets (^32 flips slot bit2: other K-half)
    int aoff[8], boff[4];
    #pragma unroll
    for (int fm = 0; fm < 8; ++fm) {
        int r = wm * 128 + fm * 16 + (lane & 15);
        aoff[fm] = r * 64 + (((lane >> 4) ^ (r & 7)) * 8);
    }
    #pragma unroll
    for (int fn = 0; fn < 4; ++fn) {
        int r = wn * 64 + fn * 16 + (lane & 15);
        boff[fn] = r * 64 + (((lane >> 4) ^ (r & 7)) * 8);
    }

    f32x4 acc[8][4];
    #pragma unroll
    for (int i = 0; i < 8; ++i)
        #pragma unroll
        for (int jj = 0; jj < 4; ++jj) acc[i][jj] = (f32x4){0.f, 0.f, 0.f, 0.f};

    // prologue: g1(0)+g2(0)+g1(1) = 14 in flight; vmcnt(8) retires g1(0)
    ISSUE_G1(0); ISSUE_G2(0); ISSUE_G1(1);
    asm volatile("s_waitcnt vmcnt(8)" ::: "memory");
    BARRIER();

    // ---- main loop: K = 2048, 32 K-tiles of BK=64, 2 regions each ----
    for (int kt = 0; kt < 32; ++kt) {
        const int abase = (kt & 1) * 16384;
        const int bbase = 32768 + (kt & 1) * 16384;
        bf16x8 bfrag[4][2];
        bf16x8 afr[4][2];

        // -- H0: issue g2(kt+1); read B all + A fm0-3; MFMA fm0-3 --
        if (kt < 31) ISSUE_G2(kt + 1);
        #pragma unroll
        for (int fn = 0; fn < 4; ++fn) {
            bfrag[fn][0] = *(const bf16x8*)&lds[bbase + boff[fn]];
            bfrag[fn][1] = *(const bf16x8*)&lds[bbase + (boff[fn] ^ 32)];
        }
        #pragma unroll
        for (int i = 0; i < 4; ++i) {
            afr[i][0] = *(const bf16x8*)&lds[abase + aoff[i]];
            afr[i][1] = *(const bf16x8*)&lds[abase + (aoff[i] ^ 32)];
        }
        #pragma unroll
        for (int kk = 0; kk < 2; ++kk)
            #pragma unroll
            for (int i = 0; i < 4; ++i)
                #pragma unroll
                for (int fn = 0; fn < 4; ++fn)
                    acc[i][fn] = __builtin_amdgcn_mfma_f32_16x16x32_bf16(
                        afr[i][kk], bfrag[fn][kk], acc[i][fn], 0, 0, 0);
        if (kt < 31) asm volatile("s_waitcnt vmcnt(8) lgkmcnt(0)" ::: "memory");
        else         asm volatile("s_waitcnt vmcnt(0) lgkmcnt(0)" ::: "memory");
        BARRIER();                                  // publishes g2(kt) (A-odd)

        // -- H1: issue g1(kt+2); read A fm4-7; MFMA fm4-7 --
        if (kt < 30) ISSUE_G1(kt + 2);
        #pragma unroll
        for (int i = 0; i < 4; ++i) {
            afr[i][0] = *(const bf16x8*)&lds[abase + aoff[4 + i]];
            afr[i][1] = *(const bf16x8*)&lds[abase + (aoff[4 + i] ^ 32)];
        }
        #pragma unroll
        for (int kk = 0; kk < 2; ++kk)
            #pragma unroll
            for (int i = 0; i < 4; ++i)
                #pragma unroll
                for (int fn = 0; fn < 4; ++fn)
                    acc[4 + i][fn] = __builtin_amdgcn_mfma_f32_16x16x32_bf16(
                        afr[i][kk], bfrag[fn][kk], acc[4 + i][fn], 0, 0, 0);
        if (kt < 30)       asm volatile("s_waitcnt vmcnt(8) lgkmcnt(0)" ::: "memory");
        else if (kt == 30) asm volatile("s_waitcnt vmcnt(2) lgkmcnt(0)" ::: "memory");
        else               asm volatile("s_waitcnt lgkmcnt(0)" ::: "memory");
        BARRIER();                                  // publishes g1(kt+1)
    }

    // ---- correction phase (LDS buffers now free; vmcnt==0 here) ----
    // (a) caug -> B0 region (DMA, drained before (d))
    {
        const __bf16* gC = caug + (size_t)(n0 + srow) * KE + sseg * 8;
        #pragma unroll
        for (int q = 0; q < 4; ++q)
            __builtin_amdgcn_global_load_lds((GLOBAL_AS void*)(gC + q * 64 * KE),
                (LDS_AS void*)&lds[32768 + q * 4096 + lbase], 16, 0, 0);
    }
    // (b) logits: sum plog[b*128 .. +128][8] -> softmax factors f[8]
    float* scr = (float*)&lds[16384];           // overlay on A1 (512 + 8 f32)
    float* lgs = scr + 512;
    {
        const float* pb = plog + (size_t)b * 128 * 8;
        int e = t & 7, rr = t >> 3;             // rr 0..63
        scr[rr * 8 + e] = pb[rr * 8 + e] + pb[(rr + 64) * 8 + e];
    }
    asm volatile("s_waitcnt lgkmcnt(0)" ::: "memory");
    BARRIER();
    if (t < 8) {
        float s = 0.f;
        #pragma unroll
        for (int i = 0; i < 64; ++i) s += scr[i * 8 + t];
        lgs[t] = s;
    }
    asm volatile("s_waitcnt lgkmcnt(0)" ::: "memory");
    BARRIER();
    float f[NEXP];
    {
        float li[NEXP];
        #pragma unroll
        for (int e = 0; e < NEXP; ++e) li[e] = lgs[e] * (1.0f / (float)SEQ);
        float mx = li[0];
        #pragma unroll
        for (int e = 1; e < NEXP; ++e) mx = fmaxf(mx, li[e]);
        float den = 0.f;
        #pragma unroll
        for (int e = 0; e < NEXP; ++e) { f[e] = expf(li[e] - mx); den += f[e]; }
        float rden = 1.0f / den;
        #pragma unroll
        for (int e = 0; e < NEXP; ++e) f[e] *= rden;
    }
    // (c) build scaled tb tile into A0 (swizzled layout the readers expect)
    #pragma unroll
    for (int q = 0; q < 4; ++q) {
        int row = q * 64 + srow;
        const __bf16* p0 = pt + (size_t)(m0 + row) * KE + sseg * 8;
        float sum[8] = {0.f, 0.f, 0.f, 0.f, 0.f, 0.f, 0.f, 0.f};
        #pragma unroll
        for (int kc = 0; kc < NKC; ++kc) {
            bf16x8 v = *(const bf16x8*)(p0 + (size_t)kc * MTOT * KE);
            #pragma unroll
            for (int jj = 0; jj < 8; ++jj) sum[jj] += (float)v[jj];
        }
        float fe = f[sseg];                     // chunk spans exactly one expert
        bf16x8 h;
        #pragma unroll
        for (int jj = 0; jj < 8; ++jj) h[jj] = (__bf16)(sum[jj] * fe);
        *(bf16x8*)&lds[row * 64 + (t & 7) * 8] = h;
    }
    asm volatile("s_waitcnt vmcnt(0) lgkmcnt(0)" ::: "memory");
    BARRIER();
    // (d) correction MFMAs (K=64)
    {
        bf16x8 bfrag[4][2];
        #pragma unroll
        for (int fn = 0; fn < 4; ++fn) {
            bfrag[fn][0] = *(const bf16x8*)&lds[32768 + boff[fn]];
            bfrag[fn][1] = *(const bf16x8*)&lds[32768 + (boff[fn] ^ 32)];
        }
        #pragma unroll
        for (int fm = 0; fm < 8; ++fm) {
            bf16x8 a0 = *(const bf16x8*)&lds[aoff[fm]];
            bf16x8 a1 = *(const bf16x8*)&lds[aoff[fm] ^ 32];
            #pragma unroll
            for (int fn = 0; fn < 4; ++fn) {
                acc[fm][fn] = __builtin_amdgcn_mfma_f32_16x16x32_bf16(
                    a0, bfrag[fn][0], acc[fm][fn], 0, 0, 0);
                acc[fm][fn] = __builtin_amdgcn_mfma_f32_16x16x32_bf16(
                    a1, bfrag[fn][1], acc[fm][fn], 0, 0, 0);
            }
        }
    }

    // ---- epilogue: bias + fp32 store ----
    #pragma unroll
    for (int fn = 0; fn < 4; ++fn) {
        int col = n0 + wn * 64 + fn * 16 + (lane & 15);
        float bv = bias[col];
        #pragma unroll
        for (int fm = 0; fm < 8; ++fm) {
            int row = m0 + wm * 128 + fm * 16 + (lane >> 4) * 4;
            #pragma unroll
            for (int v = 0; v < 4; ++v)
                out[(size_t)(row + v) * DOUT + col] = acc[fm][fn][v] + bv;
        }
    }
}

// ---------------------------------------------------------------------------
// Workspace (bytes):
//   xb   @ 0         : 33,554,432   (8192x2048 bf16)
//   Wb   @ 33554432  :  8,388,608   (2048x2048 bf16, shared LoRA folded)
//   pt   @ 41943040  :  8,388,608   (8x8192x64 bf16)
//   caug @ 50331648  :    262,144   (2048x64 bf16)
//   plog @ 50593792  :     16,384   (512x8 f32, fully overwritten)
// ---------------------------------------------------------------------------
extern "C" void kernel_launch(void* const* d_in, const int* in_sizes, int n_in,
                              void* d_out, int out_size, void* d_ws, size_t ws_size,
                              hipStream_t stream)
{
    const float* x        = (const float*)d_in[0];
    const float* base_W   = (const float*)d_in[1];
    const float* base_b   = (const float*)d_in[2];
    const float* shared_A = (const float*)d_in[3];
    const float* shared_B = (const float*)d_in[4];
    const float* expert_A = (const float*)d_in[5];
    const float* expert_B = (const float*)d_in[6];
    const float* task_emb = (const float*)d_in[7];
    const float* collab_w = (const float*)d_in[8];
    float* out = (float*)d_out;

    char* ws = (char*)d_ws;
    __bf16* xb   = (__bf16*)(ws + 0);
    __bf16* Wb   = (__bf16*)(ws + 33554432);
    __bf16* pt   = (__bf16*)(ws + 41943040);
    __bf16* caug = (__bf16*)(ws + 50331648);
    float*  plog = (float*) (ws + 50593792);

    mega_prep<<<dim3(4736), 256, 0, stream>>>(x, base_W, expert_A, shared_A,
                                              expert_B, shared_B, task_emb, collab_w,
                                              xb, Wb, caug, pt, plog);
    gemm_main<<<dim3(256), 512, 0, stream>>>(xb, Wb, pt, caug, plog, base_b, out);
}